// Round 13
// baseline (3041.131 us; speedup 1.0000x reference)
//
#include <hip/hip_runtime.h>
#include <math.h>

#define N_NODES 50000
#define N_EDGES 500000
#define N_GRAPHS 2048
#define HID 128
#define EDIM 12
#define NLAYERS 8
#define EPS_BN 1e-5f
#define LOG2E 1.44269504088896340736f

typedef __attribute__((ext_vector_type(8))) short short8;
typedef __attribute__((ext_vector_type(4))) float f32x4;
typedef __attribute__((ext_vector_type(2))) float f32x2;
typedef unsigned int uint;
typedef unsigned short ushort;

__device__ inline ushort f2bf(float x) {
  unsigned u = __float_as_uint(x);
  u = (u + 0x7FFFu + ((u >> 16) & 1u)) >> 16;  // RNE
  return (ushort)u;
}
__device__ inline unsigned pk_bf16(float a, float b) {
  return (unsigned)f2bf(a) | ((unsigned)f2bf(b) << 16);
}
__device__ inline float bflo(uint q) { return __uint_as_float(q << 16); }
__device__ inline float bfhi(uint q) { return __uint_as_float(q & 0xFFFF0000u); }
__device__ inline f32x2 pfma(f32x2 a, f32x2 b, f32x2 c) {
  return __builtin_elementwise_fma(a, b, c);
}
// butterfly add, pure-VALU DPP (ctrl must be a literal)
template <int CTRL>
__device__ inline float dpp_add(float v) {
  int s = __builtin_amdgcn_update_dpp(0, __float_as_int(v), CTRL, 0xF, 0xF, true);
  return v + __int_as_float(s);
}
// 4-lane butterfly (head = 4 lanes x 8ch): quad_perm swaps
#define RED4(v)               \
  v = dpp_add<0xB1>(v);       \
  v = dpp_add<0x4E>(v);

// ---------------- CSR build ----------------
__global__ void zero_kernel(int* deg, int* cursor, float* stats, uint* erec) {
  int i = blockIdx.x * 256 + threadIdx.x;
  if (i < N_NODES) { deg[i] = 0; cursor[i] = 0; }
  if (i < NLAYERS * 256) stats[i] = 0.f;
  if (i < 32) erec[(size_t)N_EDGES * 8 + i] = 0u;  // 4 pad records (src=0)
}

__global__ void count_kernel(const int* __restrict__ dst, int* __restrict__ deg) {
  int e = blockIdx.x * 256 + threadIdx.x;
  if (e < N_EDGES) atomicAdd(&deg[dst[e]], 1);
}

__global__ void scan1_kernel(int* __restrict__ off, int* __restrict__ bsum) {
  __shared__ int s[256];
  int t = threadIdx.x; int n = blockIdx.x * 256 + t;
  int x = (n < N_NODES) ? off[n] : 0;
  s[t] = x; __syncthreads();
  for (int o = 1; o < 256; o <<= 1) {
    int v = (t >= o) ? s[t - o] : 0;
    __syncthreads(); s[t] += v; __syncthreads();
  }
  if (n < N_NODES) off[n] = s[t] - x;
  if (t == 255) bsum[blockIdx.x] = s[255];
}

__global__ void scan2_kernel(int* __restrict__ bsum, int nb) {
  __shared__ int s[256];
  int t = threadIdx.x;
  int x = (t < nb) ? bsum[t] : 0;
  s[t] = x; __syncthreads();
  for (int o = 1; o < 256; o <<= 1) {
    int v = (t >= o) ? s[t - o] : 0;
    __syncthreads(); s[t] += v; __syncthreads();
  }
  if (t < nb) bsum[t] = s[t] - x;
}

__global__ void scan3_kernel(int* __restrict__ off, const int* __restrict__ bsum) {
  int t = threadIdx.x; int n = blockIdx.x * 256 + t;
  if (n < N_NODES) off[n] += bsum[blockIdx.x];
  if (n == 0 && blockIdx.x == 0) off[N_NODES] = N_EDGES;
}

// erec[pos] = {src, pad, ea_bf16 x6} (8 dwords, 32B)
__global__ void scatter_kernel(const int* __restrict__ src, const int* __restrict__ dst,
                               const float* __restrict__ ea,
                               const int* __restrict__ off, int* __restrict__ cursor,
                               uint* __restrict__ erec) {
  int e = blockIdx.x * 256 + threadIdx.x;
  if (e < N_EDGES) {
    int d = dst[e];
    int p = atomicAdd(&cursor[d], 1);
    int pos = off[d] + p;
    const float* eap = &ea[(size_t)e * EDIM];
    float4 e0 = *(const float4*)eap;
    float4 e1 = *(const float4*)(eap + 4);
    float4 e2 = *(const float4*)(eap + 8);
    uint4 q0, q1;
    q0.x = (uint)src[e]; q0.y = 0u;
    q0.z = pk_bf16(e0.x, e0.y); q0.w = pk_bf16(e0.z, e0.w);
    q1.x = pk_bf16(e1.x, e1.y); q1.y = pk_bf16(e1.z, e1.w);
    q1.z = pk_bf16(e2.x, e2.y); q1.w = pk_bf16(e2.z, e2.w);
    uint* o = &erec[(size_t)pos * 8];
    *(uint4*)o = q0;
    *(uint4*)(o + 4) = q1;
  }
}

// ---------------- weight packing for MFMA fragments ----------------
__global__ void wprep_kernel(const float* __restrict__ Wl, const float* __restrict__ Wr,
                             ushort* __restrict__ wpk) {
  int idx = blockIdx.x * 256 + threadIdx.x;
  if (idx >= NLAYERS * 4 * 256 * 32) return;
  int kk = idx & 31;
  int cc = (idx >> 5) & 255;
  int kb = (idx >> 13) & 3;
  int layer = idx >> 15;
  int k = kb * 32 + kk;
  float v = (cc < 128) ? Wl[((size_t)layer * 128 + k) * 128 + cc]
                       : Wr[((size_t)layer * 128 + k) * 128 + (cc - 128)];
  wpk[idx] = f2bf(v);
}

__global__ void wprep_pol_kernel(const float* __restrict__ Wp1, ushort* __restrict__ wppk) {
  int idx = blockIdx.x * 256 + threadIdx.x;
  if (idx >= 4 * 128 * 32) return;
  int kk = idx & 31;
  int cc = (idx >> 5) & 127;
  int kb = idx >> 12;
  int k = kb * 32 + kk;
  float v = (cc < 64) ? Wp1[(size_t)k * 64 + cc] : Wp1[(size_t)(128 + k) * 64 + (cc - 64)];
  wppk[idx] = f2bf(v);
}

// ---------------- input projection (writes f32 hres + bf16 h16) ----------------
__global__ void inproj_kernel(const float* __restrict__ x, const float* __restrict__ Win,
                              const float* __restrict__ b_in, float* __restrict__ h,
                              ushort* __restrict__ h16) {
  __shared__ float xs[44];
  int t = threadIdx.x;
  int n0 = blockIdx.x * 2;
  if (t < 44) xs[t] = x[n0 * 22 + t];
  __syncthreads();
  int c = t & 127, half = t >> 7;
  int n = n0 + half;
  if (n < N_NODES) {
    float acc = b_in[c];
#pragma unroll
    for (int k = 0; k < 22; k++) acc = fmaf(xs[half * 22 + k], Win[k * HID + c], acc);
    float v = fmaxf(acc, 0.f);
    h[(size_t)n * HID + c] = v;
    h16[(size_t)n * HID + c] = f2bf(v);
  }
}

// ---------------- MFMA GEMM (optionally BN+residual+relu fused on input) --------
template <int NOUT, int SPLIT, bool BIAS, bool OUTBF16, bool BNFUSE, bool RESID, bool WRITEH>
__global__ __launch_bounds__(256) void gemm_mfma_kernel(
    const ushort* __restrict__ A16, const ushort* __restrict__ T16,
    const float* __restrict__ stats, const float* __restrict__ gamma,
    const float* __restrict__ beta, const float* __restrict__ res,
    float* __restrict__ hout,
    const ushort* __restrict__ Wpk, const float* __restrict__ b1,
    const float* __restrict__ b2, void* __restrict__ C1v, void* __restrict__ C2v,
    int nrows) {
  __shared__ ushort As[64][136];  // +8 pad
  int t = threadIdx.x;
  int brow = blockIdx.x * 64;
  if constexpr (!BNFUSE) {
#pragma unroll
    for (int i = 0; i < 4; i++) {
      int f = t + i * 256;
      int r = f >> 4, cg = (f & 15) * 8;
      int g = brow + r;
      uint4 v = make_uint4(0, 0, 0, 0);
      if (g < nrows) v = *(const uint4*)&A16[(size_t)g * HID + cg];
      *(uint4*)&As[r][cg] = v;
    }
  } else {
    int cg = (t & 31) * 4;
    int r0 = t >> 5;
    const float invN = 1.f / (float)N_NODES;
    float4 sm = *(const float4*)&stats[cg];
    float4 sq = *(const float4*)&stats[128 + cg];
    float4 gm = *(const float4*)&gamma[cg];
    float4 bt = *(const float4*)&beta[cg];
    float s4[4] = {sm.x, sm.y, sm.z, sm.w};
    float q4[4] = {sq.x, sq.y, sq.z, sq.w};
    float g4[4] = {gm.x, gm.y, gm.z, gm.w};
    float bb4[4] = {bt.x, bt.y, bt.z, bt.w};
    float scl[4], shf[4];
#pragma unroll
    for (int k = 0; k < 4; k++) {
      float mu = s4[k] * invN;
      float var = q4[k] * invN - mu * mu;
      float rs = rsqrtf(var + EPS_BN);
      scl[k] = g4[k] * rs;
      shf[k] = bb4[k] - mu * scl[k];
    }
#pragma unroll
    for (int rr = 0; rr < 8; rr++) {
      int r = r0 + rr * 8;
      int g = brow + r;
      uint2 tvu = make_uint2(0u, 0u);
      if (g < nrows) tvu = *(const uint2*)&T16[(size_t)g * HID + cg];
      float o0 = fmaf(bflo(tvu.x), scl[0], shf[0]);
      float o1 = fmaf(bfhi(tvu.x), scl[1], shf[1]);
      float o2 = fmaf(bflo(tvu.y), scl[2], shf[2]);
      float o3 = fmaf(bfhi(tvu.y), scl[3], shf[3]);
      if constexpr (RESID) {
        if (g < nrows) {
          float4 rv = *(const float4*)&res[(size_t)g * HID + cg];
          o0 += rv.x; o1 += rv.y; o2 += rv.z; o3 += rv.w;
        }
      }
      o0 = fmaxf(o0, 0.f); o1 = fmaxf(o1, 0.f);
      o2 = fmaxf(o2, 0.f); o3 = fmaxf(o3, 0.f);
      if constexpr (WRITEH) {
        if (g < nrows) {
          float4 ov = make_float4(o0, o1, o2, o3);
          *(float4*)&hout[(size_t)g * HID + cg] = ov;
        }
      }
      *(uint2*)&As[r][cg] = make_uint2(pk_bf16(o0, o1), pk_bf16(o2, o3));
    }
  }
  __syncthreads();
  int lane = t & 63, wave = t >> 6;
  int arow = wave * 16 + (lane & 15);
  int k8 = (lane >> 4) * 8;
  constexpr int NT = NOUT / 16;
  f32x4 acc[NT];
#pragma unroll
  for (int n = 0; n < NT; n++) acc[n] = (f32x4){0.f, 0.f, 0.f, 0.f};
#pragma unroll
  for (int kb = 0; kb < 4; kb++) {
    short8 a = *(const short8*)&As[arow][kb * 32 + k8];
#pragma unroll
    for (int n = 0; n < NT; n++) {
      int col = n * 16 + (lane & 15);
      short8 b = *(const short8*)&Wpk[((size_t)(kb * NOUT + col)) * 32 + k8];
      acc[n] = __builtin_amdgcn_mfma_f32_16x16x32_bf16(a, b, acc[n], 0, 0, 0);
    }
  }
  // C/D: col = lane&15, row = (lane>>4)*4 + j
  int rbase = brow + wave * 16 + (lane >> 4) * 4;
  int ccol = lane & 15;
#pragma unroll
  for (int n = 0; n < NT; n++) {
    int col = n * 16 + ccol;
    float bias = 0.f;
    if (BIAS) bias = (col < SPLIT) ? b1[col] : b2[col - SPLIT];
    int colw = (col < SPLIT) ? col : col - SPLIT;
#pragma unroll
    for (int j = 0; j < 4; j++) {
      int row = rbase + j;
      if (row < nrows) {
        float v = acc[n][j] + bias;
        if (OUTBF16) {
          ushort* dstp = (ushort*)((col < SPLIT) ? C1v : C2v);
          dstp[(size_t)row * SPLIT + colw] = f2bf(v);
        } else {
          float* dstp = (float*)((col < SPLIT) ? C1v : C2v);
          dstp[(size_t)row * SPLIT + colw] = v;
        }
      }
    }
  }
}

// ---------------- GATv2 aggregation ----------------
// 4 nodes/block (256 thr), 1 node/wave, 4 EDGES per wave: quad = lane>>4 handles
// edges 4i+quad; 8 channels/lane (c0 = (lane&15)*8). Independent online-softmax
// chain per quad, merged via shfl_xor(16/32). 4-lane DPP head reduce. exp2 softmax.
#define GAT_EDGE8(ra, rb, xw, OKEXPR)                                        \
  {                                                                          \
    f32x2 xa01 = (f32x2){bflo(xw.x), bfhi(xw.x)};                            \
    f32x2 xa23 = (f32x2){bflo(xw.y), bfhi(xw.y)};                            \
    f32x2 xa45 = (f32x2){bflo(xw.z), bfhi(xw.z)};                            \
    f32x2 xa67 = (f32x2){bflo(xw.w), bfhi(xw.w)};                            \
    f32x2 ep01 = xa01 + xr01;                                                \
    f32x2 ep23 = xa23 + xr23;                                                \
    f32x2 ep45 = xa45 + xr45;                                                \
    f32x2 ep67 = xa67 + xr67;                                                \
    uint q; f32x2 bl, bh;                                                    \
    q = ra.z; bl = (f32x2){bflo(q), bflo(q)}; bh = (f32x2){bfhi(q), bfhi(q)};\
    ep01 = pfma(bl, wkg0[0], ep01); ep23 = pfma(bl, wkg1[0], ep23);          \
    ep45 = pfma(bl, wkg2[0], ep45); ep67 = pfma(bl, wkg3[0], ep67);          \
    ep01 = pfma(bh, wkg0[1], ep01); ep23 = pfma(bh, wkg1[1], ep23);          \
    ep45 = pfma(bh, wkg2[1], ep45); ep67 = pfma(bh, wkg3[1], ep67);          \
    q = ra.w; bl = (f32x2){bflo(q), bflo(q)}; bh = (f32x2){bfhi(q), bfhi(q)};\
    ep01 = pfma(bl, wkg0[2], ep01); ep23 = pfma(bl, wkg1[2], ep23);          \
    ep45 = pfma(bl, wkg2[2], ep45); ep67 = pfma(bl, wkg3[2], ep67);          \
    ep01 = pfma(bh, wkg0[3], ep01); ep23 = pfma(bh, wkg1[3], ep23);          \
    ep45 = pfma(bh, wkg2[3], ep45); ep67 = pfma(bh, wkg3[3], ep67);          \
    q = rb.x; bl = (f32x2){bflo(q), bflo(q)}; bh = (f32x2){bfhi(q), bfhi(q)};\
    ep01 = pfma(bl, wkg0[4], ep01); ep23 = pfma(bl, wkg1[4], ep23);          \
    ep45 = pfma(bl, wkg2[4], ep45); ep67 = pfma(bl, wkg3[4], ep67);          \
    ep01 = pfma(bh, wkg0[5], ep01); ep23 = pfma(bh, wkg1[5], ep23);          \
    ep45 = pfma(bh, wkg2[5], ep45); ep67 = pfma(bh, wkg3[5], ep67);          \
    q = rb.y; bl = (f32x2){bflo(q), bflo(q)}; bh = (f32x2){bfhi(q), bfhi(q)};\
    ep01 = pfma(bl, wkg0[6], ep01); ep23 = pfma(bl, wkg1[6], ep23);          \
    ep45 = pfma(bl, wkg2[6], ep45); ep67 = pfma(bl, wkg3[6], ep67);          \
    ep01 = pfma(bh, wkg0[7], ep01); ep23 = pfma(bh, wkg1[7], ep23);          \
    ep45 = pfma(bh, wkg2[7], ep45); ep67 = pfma(bh, wkg3[7], ep67);          \
    q = rb.z; bl = (f32x2){bflo(q), bflo(q)}; bh = (f32x2){bfhi(q), bfhi(q)};\
    ep01 = pfma(bl, wkg0[8], ep01); ep23 = pfma(bl, wkg1[8], ep23);          \
    ep45 = pfma(bl, wkg2[8], ep45); ep67 = pfma(bl, wkg3[8], ep67);          \
    ep01 = pfma(bh, wkg0[9], ep01); ep23 = pfma(bh, wkg1[9], ep23);          \
    ep45 = pfma(bh, wkg2[9], ep45); ep67 = pfma(bh, wkg3[9], ep67);          \
    q = rb.w; bl = (f32x2){bflo(q), bflo(q)}; bh = (f32x2){bfhi(q), bfhi(q)};\
    ep01 = pfma(bl, wkg0[10], ep01); ep23 = pfma(bl, wkg1[10], ep23);        \
    ep45 = pfma(bl, wkg2[10], ep45); ep67 = pfma(bl, wkg3[10], ep67);        \
    ep01 = pfma(bh, wkg0[11], ep01); ep23 = pfma(bh, wkg1[11], ep23);        \
    ep45 = pfma(bh, wkg2[11], ep45); ep67 = pfma(bh, wkg3[11], ep67);        \
    f32x2 s01 = __builtin_elementwise_max(ep01, ep01 * (f32x2){0.2f, 0.2f}); \
    f32x2 s23 = __builtin_elementwise_max(ep23, ep23 * (f32x2){0.2f, 0.2f}); \
    f32x2 s45 = __builtin_elementwise_max(ep45, ep45 * (f32x2){0.2f, 0.2f}); \
    f32x2 s67 = __builtin_elementwise_max(ep67, ep67 * (f32x2){0.2f, 0.2f}); \
    f32x2 pv = s01 * at01;                                                   \
    pv = pfma(s23, at23, pv);                                                \
    pv = pfma(s45, at45, pv);                                                \
    pv = pfma(s67, at67, pv);                                                \
    float v = pv.x + pv.y;                                                   \
    RED4(v)                                                                  \
    bool ok = (OKEXPR);                                                      \
    float dm = v - m;                                                        \
    float e = __builtin_amdgcn_exp2f(-fabsf(dm));                            \
    bool big = dm > 0.f;                                                     \
    float sc = (big && ok) ? e : 1.f;                                        \
    float p = ok ? (big ? 1.f : e) : 0.f;                                    \
    m = (ok && big) ? v : m;                                                 \
    d = fmaf(d, sc, p);                                                      \
    f32x2 scv = (f32x2){sc, sc}, pvv = (f32x2){p, p};                        \
    acc01 = pfma(acc01, scv, pvv * xa01);                                    \
    acc23 = pfma(acc23, scv, pvv * xa23);                                    \
    acc45 = pfma(acc45, scv, pvv * xa45);                                    \
    acc67 = pfma(acc67, scv, pvv * xa67);                                    \
  }

__global__ __launch_bounds__(256, 4) void gat_kernel(
    const ushort* __restrict__ xl16, const ushort* __restrict__ xr16,
    const uint* __restrict__ erec, const int* __restrict__ off,
    const float* __restrict__ Wel, const float* __restrict__ attl,
    const float* __restrict__ bol, ushort* __restrict__ out16) {
  int lane = threadIdx.x & 63;
  int node = blockIdx.x * 4 + (threadIdx.x >> 6);
  if (node >= N_NODES) return;
  int quad = lane >> 4;          // edge slot 0..3
  int c0 = (lane & 15) * 8;      // 8 channels per lane (head = 4 lanes)

  f32x2 wkg0[12], wkg1[12], wkg2[12], wkg3[12];
#pragma unroll
  for (int k = 0; k < 12; k++) {
    float4 a = *(const float4*)&Wel[k * HID + c0];
    float4 b = *(const float4*)&Wel[k * HID + c0 + 4];
    wkg0[k] = (f32x2){a.x, a.y};
    wkg1[k] = (f32x2){a.z, a.w};
    wkg2[k] = (f32x2){b.x, b.y};
    wkg3[k] = (f32x2){b.z, b.w};
  }
  float4 ata = *(const float4*)&attl[c0];
  float4 atb = *(const float4*)&attl[c0 + 4];
  f32x2 at01 = (f32x2){ata.x * LOG2E, ata.y * LOG2E};
  f32x2 at23 = (f32x2){ata.z * LOG2E, ata.w * LOG2E};
  f32x2 at45 = (f32x2){atb.x * LOG2E, atb.y * LOG2E};
  f32x2 at67 = (f32x2){atb.z * LOG2E, atb.w * LOG2E};
  uint4 xru = *(const uint4*)&xr16[((uint)node << 7) + c0];
  f32x2 xr01 = (f32x2){bflo(xru.x), bfhi(xru.x)};
  f32x2 xr23 = (f32x2){bflo(xru.y), bfhi(xru.y)};
  f32x2 xr45 = (f32x2){bflo(xru.z), bfhi(xru.z)};
  f32x2 xr67 = (f32x2){bflo(xru.w), bfhi(xru.w)};

  int is = off[node], deg = off[node + 1] - is;

  float m = -INFINITY, d = 0.f;
  f32x2 acc01 = (f32x2){0.f, 0.f};
  f32x2 acc23 = (f32x2){0.f, 0.f};
  f32x2 acc45 = (f32x2){0.f, 0.f};
  f32x2 acc67 = (f32x2){0.f, 0.f};

  if (deg > 0) {
    // clamp prologue index so quads beyond deg don't fetch stray rows
    int first = is + ((quad < deg) ? quad : 0);
    const uint* pe = erec + (size_t)first * 8;
    uint4 Ra = *(const uint4*)pe, Rb = *(const uint4*)(pe + 4);
    uint4 xw = *(const uint4*)&xl16[(Ra.x << 7) + c0];
    int full = deg >> 2;
    for (int i = 0; i < full; i++) {
      const uint* pn = pe + 32;                         // next record for this quad
      uint4 Na = *(const uint4*)pn, Nb = *(const uint4*)(pn + 4);
      uint4 xn = *(const uint4*)&xl16[(Na.x << 7) + c0];
      GAT_EDGE8(Ra, Rb, xw, true)
      Ra = Na; Rb = Nb; xw = xn; pe = pn;
    }
    if (deg & 3) GAT_EDGE8(Ra, Rb, xw, quad < (deg & 3))
  }

  // merge the 4 quad-chains (same channels live in lanes l^16, l^32)
#pragma unroll
  for (int ofs = 16; ofs <= 32; ofs <<= 1) {
    float mo = __shfl_xor(m, ofs);
    float dd = __shfl_xor(d, ofs);
    f32x2 o01, o23, o45, o67;
    o01.x = __shfl_xor(acc01.x, ofs); o01.y = __shfl_xor(acc01.y, ofs);
    o23.x = __shfl_xor(acc23.x, ofs); o23.y = __shfl_xor(acc23.y, ofs);
    o45.x = __shfl_xor(acc45.x, ofs); o45.y = __shfl_xor(acc45.y, ofs);
    o67.x = __shfl_xor(acc67.x, ofs); o67.y = __shfl_xor(acc67.y, ofs);
    float mn = fmaxf(m, mo);
    float wS = (m > -INFINITY) ? __builtin_amdgcn_exp2f(m - mn) : 0.f;
    float wO = (mo > -INFINITY) ? __builtin_amdgcn_exp2f(mo - mn) : 0.f;
    d = d * wS + dd * wO;
    f32x2 wSv = (f32x2){wS, wS}, wOv = (f32x2){wO, wO};
    acc01 = acc01 * wSv + o01 * wOv;
    acc23 = acc23 * wSv + o23 * wOv;
    acc45 = acc45 * wSv + o45 * wOv;
    acc67 = acc67 * wSv + o67 * wOv;
    m = mn;
  }
  float inv = 1.f / (d + 1e-16f);
  if ((lane & 48) == 0) {   // lanes 0-15 of the wave
    float4 boa = *(const float4*)&bol[c0];
    float4 bob = *(const float4*)&bol[c0 + 4];
    uint4 o;
    o.x = pk_bf16(fmaf(acc01.x, inv, boa.x), fmaf(acc01.y, inv, boa.y));
    o.y = pk_bf16(fmaf(acc23.x, inv, boa.z), fmaf(acc23.y, inv, boa.w));
    o.z = pk_bf16(fmaf(acc45.x, inv, bob.x), fmaf(acc45.y, inv, bob.y));
    o.w = pk_bf16(fmaf(acc67.x, inv, bob.z), fmaf(acc67.y, inv, bob.w));
    *(uint4*)&out16[((uint)node << 7) + c0] = o;
  }
}

// ---------------- BatchNorm stats (bf16 input) ----------------
__global__ void bnstats_kernel(const ushort* __restrict__ t16, float* __restrict__ sums) {
  int tid = threadIdx.x;
  int c2 = (tid & 63) * 2;     // channel pair
  int grp = tid >> 6;          // 0..3 row groups
  float s0 = 0.f, s1 = 0.f, q0 = 0.f, q1 = 0.f;
  for (int n = blockIdx.x * 4 + grp; n < N_NODES; n += 1024) {
    uint v = *(const uint*)&t16[((uint)n << 7) + c2];
    float a = bflo(v), b = bfhi(v);
    s0 += a; q0 = fmaf(a, a, q0);
    s1 += b; q1 = fmaf(b, b, q1);
  }
  __shared__ float ls[4][128], lq[4][128];
  *(float2*)&ls[grp][c2] = make_float2(s0, s1);
  *(float2*)&lq[grp][c2] = make_float2(q0, q1);
  __syncthreads();
  if (tid < 128) {
    float s = ls[0][tid] + ls[1][tid] + ls[2][tid] + ls[3][tid];
    atomicAdd(&sums[tid], s);
    float q = lq[0][tid] + lq[1][tid] + lq[2][tid] + lq[3][tid];
    atomicAdd(&sums[128 + tid], q);
  }
}

// ---------------- policy head (one edge per 16 lanes, grid-stride) ----------------
__global__ __launch_bounds__(256) void policy_kernel(
    const ushort* __restrict__ Ps, const ushort* __restrict__ Pd,
    const int* __restrict__ src, const int* __restrict__ dst,
    const float* __restrict__ edge_attr, const float* __restrict__ Wp1e,
    const float* __restrict__ bp1, const float* __restrict__ Wp2,
    const float* __restrict__ bp2, float* __restrict__ outp) {
  int j = threadIdx.x & 15;
  int gid = (blockIdx.x * 256 + threadIdx.x) >> 4;
  int ngroups = (gridDim.x * 256) >> 4;
  float4 we[12];
#pragma unroll
  for (int k = 0; k < 12; k++) we[k] = *(const float4*)&Wp1e[k * 64 + j * 4];
  float4 b4 = *(const float4*)&bp1[j * 4];
  float4 w2 = *(const float4*)&Wp2[j * 4];
  float bp2c = bp2[0];
  for (int e = gid; e < N_EDGES; e += ngroups) {
    int s = src[e], d = dst[e];
    const float* eap = &edge_attr[(size_t)e * EDIM];
    float4 e0 = *(const float4*)eap;
    float4 e1 = *(const float4*)(eap + 4);
    float4 e2 = *(const float4*)(eap + 8);
    uint2 psu = *(const uint2*)&Ps[(size_t)s * 64 + j * 4];
    uint2 pdu = *(const uint2*)&Pd[(size_t)d * 64 + j * 4];
    float eav[12] = {e0.x, e0.y, e0.z, e0.w, e1.x, e1.y, e1.z, e1.w, e2.x, e2.y, e2.z, e2.w};
    float hx = bflo(psu.x) + bflo(pdu.x) + b4.x;
    float hy = bfhi(psu.x) + bfhi(pdu.x) + b4.y;
    float hz = bflo(psu.y) + bflo(pdu.y) + b4.z;
    float hw = bfhi(psu.y) + bfhi(pdu.y) + b4.w;
#pragma unroll
    for (int k = 0; k < 12; k++) {
      hx = fmaf(eav[k], we[k].x, hx);
      hy = fmaf(eav[k], we[k].y, hy);
      hz = fmaf(eav[k], we[k].z, hz);
      hw = fmaf(eav[k], we[k].w, hw);
    }
    hx = fmaxf(hx, 0.f); hy = fmaxf(hy, 0.f); hz = fmaxf(hz, 0.f); hw = fmaxf(hw, 0.f);
    float v = fmaf(hx, w2.x, fmaf(hy, w2.y, fmaf(hz, w2.z, hw * w2.w)));
    v += __shfl_xor(v, 1);
    v += __shfl_xor(v, 2);
    v += __shfl_xor(v, 4);
    v += __shfl_xor(v, 8);
    if (j == 0) outp[e] = v + bp2c;
  }
}

// ---------------- pooled mean + value head ----------------
__device__ int lower_bound_dev(const int* a, int n, int key) {
  int lo = 0, hi = n;
  while (lo < hi) {
    int mid = (lo + hi) >> 1;
    if (a[mid] < key) lo = mid + 1; else hi = mid;
  }
  return lo;
}

__global__ void poolvalue_kernel(const float* __restrict__ h, const int* __restrict__ batch,
                                 const float* __restrict__ Wv1, const float* __restrict__ bv1,
                                 const float* __restrict__ Wv2, const float* __restrict__ bv2,
                                 float* __restrict__ outv) {
  __shared__ float pl[128];
  __shared__ float hd[64];
  __shared__ int range[2];
  int g = blockIdx.x, t = threadIdx.x;
  if (t == 0) {
    range[0] = lower_bound_dev(batch, N_NODES, g);
    range[1] = lower_bound_dev(batch, N_NODES, g + 1);
  }
  __syncthreads();
  int lo = range[0], hi = range[1];
  float s = 0.f;
  for (int n = lo; n < hi; n++) s += h[(size_t)n * HID + t];
  float cnt = (float)(hi - lo);
  pl[t] = s / fmaxf(cnt, 1.f);
  __syncthreads();
  if (t < 64) {
    float a = bv1[t];
    for (int c = 0; c < 128; c++) a = fmaf(pl[c], Wv1[c * 64 + t], a);
    hd[t] = fmaxf(a, 0.f);
  }
  __syncthreads();
  if (t < 3) {
    float a = bv2[t];
    for (int j = 0; j < 64; j++) a = fmaf(hd[j], Wv2[j * 3 + t], a);
    outv[g * 3 + t] = a;
  }
}

// ---------------- host ----------------
extern "C" void kernel_launch(void* const* d_in, const int* in_sizes, int n_in,
                              void* d_out, int out_size, void* d_ws, size_t ws_size,
                              hipStream_t stream) {
  (void)in_sizes; (void)n_in; (void)out_size; (void)ws_size;
  const float* x    = (const float*)d_in[0];
  const int*   src  = (const int*)d_in[1];
  const int*   dst  = (const int*)d_in[2];
  const int*   batch= (const int*)d_in[3];
  const float* ea   = (const float*)d_in[4];
  const float* Win  = (const float*)d_in[5];
  const float* b_in = (const float*)d_in[6];
  const float* Wl   = (const float*)d_in[7];
  const float* bl   = (const float*)d_in[8];
  const float* Wr   = (const float*)d_in[9];
  const float* br   = (const float*)d_in[10];
  const float* We   = (const float*)d_in[11];
  const float* att  = (const float*)d_in[12];
  const float* bo   = (const float*)d_in[13];
  const float* gamma= (const float*)d_in[14];
  const float* beta = (const float*)d_in[15];
  const float* Wv1  = (const float*)d_in[16];
  const float* bv1  = (const float*)d_in[17];
  const float* Wv2  = (const float*)d_in[18];
  const float* bv2  = (const float*)d_in[19];
  const float* Wp1  = (const float*)d_in[20];
  const float* bp1  = (const float*)d_in[21];
  const float* Wp2  = (const float*)d_in[22];
  const float* bp2  = (const float*)d_in[23];

  float* outv = (float*)d_out;                      // [G,3]
  float* outp = outv + (size_t)N_GRAPHS * 3;        // [E]

  float* hres   = (float*)d_ws;                           // residual / final h (f32)
  ushort* tmp16 = (ushort*)(hres + (size_t)N_NODES * HID); // gat output (bf16)
  ushort* h16   = tmp16 + (size_t)N_NODES * HID;           // inproj bf16
  ushort* xl16  = h16 + (size_t)N_NODES * HID;
  ushort* xr16  = xl16 + (size_t)N_NODES * HID;
  float* stats  = (float*)(xr16 + (size_t)N_NODES * HID);
  ushort* wpk   = (ushort*)(stats + NLAYERS * 256);
  ushort* wppk  = wpk + (size_t)NLAYERS * 4 * 256 * 32;
  int* off    = (int*)(wppk + 4 * 128 * 32);
  int* cursor = off + (N_NODES + 1);
  int* bsum   = cursor + N_NODES;
  uint* erec  = (uint*)(((uintptr_t)(bsum + 256) + 15) & ~(uintptr_t)15);

  const int NB = (N_NODES + 255) / 256;
  const int EB = (N_EDGES + 255) / 256;

  zero_kernel<<<NB, 256, 0, stream>>>(off, cursor, stats, erec);
  count_kernel<<<EB, 256, 0, stream>>>(dst, off);
  scan1_kernel<<<NB, 256, 0, stream>>>(off, bsum);
  scan2_kernel<<<1, 256, 0, stream>>>(bsum, NB);
  scan3_kernel<<<NB, 256, 0, stream>>>(off, bsum);
  scatter_kernel<<<EB, 256, 0, stream>>>(src, dst, ea, off, cursor, erec);
  wprep_kernel<<<(NLAYERS * 4 * 256 * 32 + 255) / 256, 256, 0, stream>>>(Wl, Wr, wpk);
  wprep_pol_kernel<<<(4 * 128 * 32 + 255) / 256, 256, 0, stream>>>(Wp1, wppk);
  inproj_kernel<<<N_NODES / 2, 256, 0, stream>>>(x, Win, b_in, hres, h16);

  const int MB = (N_NODES + 63) / 64;
  const int GATB = (N_NODES + 3) / 4;

  for (int l = 0; l < NLAYERS; l++) {
    if (l == 0) {
      gemm_mfma_kernel<256, 128, true, true, false, false, false><<<MB, 256, 0, stream>>>(
          h16, nullptr, nullptr, nullptr, nullptr, nullptr, nullptr,
          wpk, bl, br, xl16, xr16, N_NODES);
    } else if (l & 1) {
      int p = l - 1;
      gemm_mfma_kernel<256, 128, true, true, true, false, false><<<MB, 256, 0, stream>>>(
          nullptr, tmp16, stats + p * 256, gamma + p * HID, beta + p * HID, nullptr, nullptr,
          wpk + (size_t)l * 32768, bl + l * HID, br + l * HID, xl16, xr16, N_NODES);
    } else {
      int p = l - 1;
      gemm_mfma_kernel<256, 128, true, true, true, true, true><<<MB, 256, 0, stream>>>(
          nullptr, tmp16, stats + p * 256, gamma + p * HID, beta + p * HID, hres, hres,
          wpk + (size_t)l * 32768, bl + l * HID, br + l * HID, xl16, xr16, N_NODES);
    }
    gat_kernel<<<GATB, 256, 0, stream>>>(xl16, xr16, erec, off,
                                         We + (size_t)l * EDIM * HID, att + (size_t)l * HID,
                                         bo + (size_t)l * HID, tmp16);
    bnstats_kernel<<<256, 256, 0, stream>>>(tmp16, stats + l * 256);
  }

  // policy projections: BN of layer 7 fused (+residual, final h -> hres), bf16 out
  ushort* Ps = xl16;
  ushort* Pd = xr16;
  gemm_mfma_kernel<128, 64, false, true, true, true, true><<<MB, 256, 0, stream>>>(
      nullptr, tmp16, stats + 7 * 256, gamma + 7 * HID, beta + 7 * HID, hres, hres,
      wppk, nullptr, nullptr, Ps, Pd, N_NODES);
  policy_kernel<<<2048, 256, 0, stream>>>(Ps, Pd, src, dst, ea,
                                          Wp1 + 256 * 64, bp1, Wp2, bp2, outp);
  poolvalue_kernel<<<N_GRAPHS, 128, 0, stream>>>(hres, batch, Wv1, bv1, Wv2, bv2, outv);
}

// Round 14
// 1503.271 us; speedup vs baseline: 2.0230x; 2.0230x over previous
//
#include <hip/hip_runtime.h>
#include <math.h>

#define N_NODES 50000
#define N_EDGES 500000
#define N_GRAPHS 2048
#define HID 128
#define EDIM 12
#define NLAYERS 8
#define EPS_BN 1e-5f
#define LOG2E 1.44269504088896340736f

typedef __attribute__((ext_vector_type(8))) short short8;
typedef __attribute__((ext_vector_type(4))) float f32x4;
typedef __attribute__((ext_vector_type(2))) float f32x2;
typedef unsigned int uint;
typedef unsigned short ushort;

__device__ inline ushort f2bf(float x) {
  unsigned u = __float_as_uint(x);
  u = (u + 0x7FFFu + ((u >> 16) & 1u)) >> 16;  // RNE
  return (ushort)u;
}
__device__ inline unsigned pk_bf16(float a, float b) {
  return (unsigned)f2bf(a) | ((unsigned)f2bf(b) << 16);
}
__device__ inline float bflo(uint q) { return __uint_as_float(q << 16); }
__device__ inline float bfhi(uint q) { return __uint_as_float(q & 0xFFFF0000u); }
__device__ inline f32x2 pfma(f32x2 a, f32x2 b, f32x2 c) {
  return __builtin_elementwise_fma(a, b, c);
}
// butterfly add, pure-VALU DPP (ctrl must be a literal)
template <int CTRL>
__device__ inline float dpp_add(float v) {
  int s = __builtin_amdgcn_update_dpp(0, __float_as_int(v), CTRL, 0xF, 0xF, true);
  return v + __int_as_float(s);
}
// 4-lane butterfly (head = 4 lanes x 8ch): quad_perm swaps
#define RED4(v)               \
  v = dpp_add<0xB1>(v);       \
  v = dpp_add<0x4E>(v);

// ---------------- CSR build ----------------
__global__ void zero_kernel(int* deg, int* cursor, float* stats, uint* erec) {
  int i = blockIdx.x * 256 + threadIdx.x;
  if (i < N_NODES) { deg[i] = 0; cursor[i] = 0; }
  if (i < NLAYERS * 256) stats[i] = 0.f;
  if (i < 32) erec[(size_t)N_EDGES * 8 + i] = 0u;  // 4 pad records (src=0)
}

__global__ void count_kernel(const int* __restrict__ dst, int* __restrict__ deg) {
  int e = blockIdx.x * 256 + threadIdx.x;
  if (e < N_EDGES) atomicAdd(&deg[dst[e]], 1);
}

__global__ void scan1_kernel(int* __restrict__ off, int* __restrict__ bsum) {
  __shared__ int s[256];
  int t = threadIdx.x; int n = blockIdx.x * 256 + t;
  int x = (n < N_NODES) ? off[n] : 0;
  s[t] = x; __syncthreads();
  for (int o = 1; o < 256; o <<= 1) {
    int v = (t >= o) ? s[t - o] : 0;
    __syncthreads(); s[t] += v; __syncthreads();
  }
  if (n < N_NODES) off[n] = s[t] - x;
  if (t == 255) bsum[blockIdx.x] = s[255];
}

__global__ void scan2_kernel(int* __restrict__ bsum, int nb) {
  __shared__ int s[256];
  int t = threadIdx.x;
  int x = (t < nb) ? bsum[t] : 0;
  s[t] = x; __syncthreads();
  for (int o = 1; o < 256; o <<= 1) {
    int v = (t >= o) ? s[t - o] : 0;
    __syncthreads(); s[t] += v; __syncthreads();
  }
  if (t < nb) bsum[t] = s[t] - x;
}

__global__ void scan3_kernel(int* __restrict__ off, const int* __restrict__ bsum) {
  int t = threadIdx.x; int n = blockIdx.x * 256 + t;
  if (n < N_NODES) off[n] += bsum[blockIdx.x];
  if (n == 0 && blockIdx.x == 0) off[N_NODES] = N_EDGES;
}

// erec[pos] = {src, pad, ea_bf16 x6} (8 dwords, 32B)
__global__ void scatter_kernel(const int* __restrict__ src, const int* __restrict__ dst,
                               const float* __restrict__ ea,
                               const int* __restrict__ off, int* __restrict__ cursor,
                               uint* __restrict__ erec) {
  int e = blockIdx.x * 256 + threadIdx.x;
  if (e < N_EDGES) {
    int d = dst[e];
    int p = atomicAdd(&cursor[d], 1);
    int pos = off[d] + p;
    const float* eap = &ea[(size_t)e * EDIM];
    float4 e0 = *(const float4*)eap;
    float4 e1 = *(const float4*)(eap + 4);
    float4 e2 = *(const float4*)(eap + 8);
    uint4 q0, q1;
    q0.x = (uint)src[e]; q0.y = 0u;
    q0.z = pk_bf16(e0.x, e0.y); q0.w = pk_bf16(e0.z, e0.w);
    q1.x = pk_bf16(e1.x, e1.y); q1.y = pk_bf16(e1.z, e1.w);
    q1.z = pk_bf16(e2.x, e2.y); q1.w = pk_bf16(e2.z, e2.w);
    uint* o = &erec[(size_t)pos * 8];
    *(uint4*)o = q0;
    *(uint4*)(o + 4) = q1;
  }
}

// ---------------- weight packing for MFMA fragments ----------------
__global__ void wprep_kernel(const float* __restrict__ Wl, const float* __restrict__ Wr,
                             ushort* __restrict__ wpk) {
  int idx = blockIdx.x * 256 + threadIdx.x;
  if (idx >= NLAYERS * 4 * 256 * 32) return;
  int kk = idx & 31;
  int cc = (idx >> 5) & 255;
  int kb = (idx >> 13) & 3;
  int layer = idx >> 15;
  int k = kb * 32 + kk;
  float v = (cc < 128) ? Wl[((size_t)layer * 128 + k) * 128 + cc]
                       : Wr[((size_t)layer * 128 + k) * 128 + (cc - 128)];
  wpk[idx] = f2bf(v);
}

__global__ void wprep_pol_kernel(const float* __restrict__ Wp1, ushort* __restrict__ wppk) {
  int idx = blockIdx.x * 256 + threadIdx.x;
  if (idx >= 4 * 128 * 32) return;
  int kk = idx & 31;
  int cc = (idx >> 5) & 127;
  int kb = idx >> 12;
  int k = kb * 32 + kk;
  float v = (cc < 64) ? Wp1[(size_t)k * 64 + cc] : Wp1[(size_t)(128 + k) * 64 + (cc - 64)];
  wppk[idx] = f2bf(v);
}

// ---------------- input projection (writes f32 hres + bf16 h16) ----------------
__global__ void inproj_kernel(const float* __restrict__ x, const float* __restrict__ Win,
                              const float* __restrict__ b_in, float* __restrict__ h,
                              ushort* __restrict__ h16) {
  __shared__ float xs[44];
  int t = threadIdx.x;
  int n0 = blockIdx.x * 2;
  if (t < 44) xs[t] = x[n0 * 22 + t];
  __syncthreads();
  int c = t & 127, half = t >> 7;
  int n = n0 + half;
  if (n < N_NODES) {
    float acc = b_in[c];
#pragma unroll
    for (int k = 0; k < 22; k++) acc = fmaf(xs[half * 22 + k], Win[k * HID + c], acc);
    float v = fmaxf(acc, 0.f);
    h[(size_t)n * HID + c] = v;
    h16[(size_t)n * HID + c] = f2bf(v);
  }
}

// ---------------- MFMA GEMM (optionally BN+residual+relu fused on input) --------
template <int NOUT, int SPLIT, bool BIAS, bool OUTBF16, bool BNFUSE, bool RESID, bool WRITEH>
__global__ __launch_bounds__(256) void gemm_mfma_kernel(
    const ushort* __restrict__ A16, const ushort* __restrict__ T16,
    const float* __restrict__ stats, const float* __restrict__ gamma,
    const float* __restrict__ beta, const float* __restrict__ res,
    float* __restrict__ hout,
    const ushort* __restrict__ Wpk, const float* __restrict__ b1,
    const float* __restrict__ b2, void* __restrict__ C1v, void* __restrict__ C2v,
    int nrows) {
  __shared__ ushort As[64][136];  // +8 pad
  int t = threadIdx.x;
  int brow = blockIdx.x * 64;
  if constexpr (!BNFUSE) {
#pragma unroll
    for (int i = 0; i < 4; i++) {
      int f = t + i * 256;
      int r = f >> 4, cg = (f & 15) * 8;
      int g = brow + r;
      uint4 v = make_uint4(0, 0, 0, 0);
      if (g < nrows) v = *(const uint4*)&A16[(size_t)g * HID + cg];
      *(uint4*)&As[r][cg] = v;
    }
  } else {
    int cg = (t & 31) * 4;
    int r0 = t >> 5;
    const float invN = 1.f / (float)N_NODES;
    float4 sm = *(const float4*)&stats[cg];
    float4 sq = *(const float4*)&stats[128 + cg];
    float4 gm = *(const float4*)&gamma[cg];
    float4 bt = *(const float4*)&beta[cg];
    float s4[4] = {sm.x, sm.y, sm.z, sm.w};
    float q4[4] = {sq.x, sq.y, sq.z, sq.w};
    float g4[4] = {gm.x, gm.y, gm.z, gm.w};
    float bb4[4] = {bt.x, bt.y, bt.z, bt.w};
    float scl[4], shf[4];
#pragma unroll
    for (int k = 0; k < 4; k++) {
      float mu = s4[k] * invN;
      float var = q4[k] * invN - mu * mu;
      float rs = rsqrtf(var + EPS_BN);
      scl[k] = g4[k] * rs;
      shf[k] = bb4[k] - mu * scl[k];
    }
#pragma unroll
    for (int rr = 0; rr < 8; rr++) {
      int r = r0 + rr * 8;
      int g = brow + r;
      uint2 tvu = make_uint2(0u, 0u);
      if (g < nrows) tvu = *(const uint2*)&T16[(size_t)g * HID + cg];
      float o0 = fmaf(bflo(tvu.x), scl[0], shf[0]);
      float o1 = fmaf(bfhi(tvu.x), scl[1], shf[1]);
      float o2 = fmaf(bflo(tvu.y), scl[2], shf[2]);
      float o3 = fmaf(bfhi(tvu.y), scl[3], shf[3]);
      if constexpr (RESID) {
        if (g < nrows) {
          float4 rv = *(const float4*)&res[(size_t)g * HID + cg];
          o0 += rv.x; o1 += rv.y; o2 += rv.z; o3 += rv.w;
        }
      }
      o0 = fmaxf(o0, 0.f); o1 = fmaxf(o1, 0.f);
      o2 = fmaxf(o2, 0.f); o3 = fmaxf(o3, 0.f);
      if constexpr (WRITEH) {
        if (g < nrows) {
          float4 ov = make_float4(o0, o1, o2, o3);
          *(float4*)&hout[(size_t)g * HID + cg] = ov;
        }
      }
      *(uint2*)&As[r][cg] = make_uint2(pk_bf16(o0, o1), pk_bf16(o2, o3));
    }
  }
  __syncthreads();
  int lane = t & 63, wave = t >> 6;
  int arow = wave * 16 + (lane & 15);
  int k8 = (lane >> 4) * 8;
  constexpr int NT = NOUT / 16;
  f32x4 acc[NT];
#pragma unroll
  for (int n = 0; n < NT; n++) acc[n] = (f32x4){0.f, 0.f, 0.f, 0.f};
#pragma unroll
  for (int kb = 0; kb < 4; kb++) {
    short8 a = *(const short8*)&As[arow][kb * 32 + k8];
#pragma unroll
    for (int n = 0; n < NT; n++) {
      int col = n * 16 + (lane & 15);
      short8 b = *(const short8*)&Wpk[((size_t)(kb * NOUT + col)) * 32 + k8];
      acc[n] = __builtin_amdgcn_mfma_f32_16x16x32_bf16(a, b, acc[n], 0, 0, 0);
    }
  }
  // C/D: col = lane&15, row = (lane>>4)*4 + j
  int rbase = brow + wave * 16 + (lane >> 4) * 4;
  int ccol = lane & 15;
#pragma unroll
  for (int n = 0; n < NT; n++) {
    int col = n * 16 + ccol;
    float bias = 0.f;
    if (BIAS) bias = (col < SPLIT) ? b1[col] : b2[col - SPLIT];
    int colw = (col < SPLIT) ? col : col - SPLIT;
#pragma unroll
    for (int j = 0; j < 4; j++) {
      int row = rbase + j;
      if (row < nrows) {
        float v = acc[n][j] + bias;
        if (OUTBF16) {
          ushort* dstp = (ushort*)((col < SPLIT) ? C1v : C2v);
          dstp[(size_t)row * SPLIT + colw] = f2bf(v);
        } else {
          float* dstp = (float*)((col < SPLIT) ? C1v : C2v);
          dstp[(size_t)row * SPLIT + colw] = v;
        }
      }
    }
  }
}

// ---------------- GATv2 aggregation ----------------
// 4 nodes/block (256 thr), 1 node/wave, 4 EDGES per wave: quad = lane>>4 handles
// edges 4i+quad; 8 channels/lane (c0 = (lane&15)*8). Independent online-softmax
// chain per quad, merged via shfl_xor(16/32). 4-lane DPP head reduce. exp2 softmax.
// NOTE: no min-waves clamp in launch_bounds — kernel needs ~150 VGPR; clamping
// to 64 (R13) produced 1 GB/dispatch of scratch-spill traffic.
#define GAT_EDGE8(ra, rb, xw, OKEXPR)                                        \
  {                                                                          \
    f32x2 xa01 = (f32x2){bflo(xw.x), bfhi(xw.x)};                            \
    f32x2 xa23 = (f32x2){bflo(xw.y), bfhi(xw.y)};                            \
    f32x2 xa45 = (f32x2){bflo(xw.z), bfhi(xw.z)};                            \
    f32x2 xa67 = (f32x2){bflo(xw.w), bfhi(xw.w)};                            \
    f32x2 ep01 = xa01 + xr01;                                                \
    f32x2 ep23 = xa23 + xr23;                                                \
    f32x2 ep45 = xa45 + xr45;                                                \
    f32x2 ep67 = xa67 + xr67;                                                \
    uint q; f32x2 bl, bh;                                                    \
    q = ra.z; bl = (f32x2){bflo(q), bflo(q)}; bh = (f32x2){bfhi(q), bfhi(q)};\
    ep01 = pfma(bl, wkg0[0], ep01); ep23 = pfma(bl, wkg1[0], ep23);          \
    ep45 = pfma(bl, wkg2[0], ep45); ep67 = pfma(bl, wkg3[0], ep67);          \
    ep01 = pfma(bh, wkg0[1], ep01); ep23 = pfma(bh, wkg1[1], ep23);          \
    ep45 = pfma(bh, wkg2[1], ep45); ep67 = pfma(bh, wkg3[1], ep67);          \
    q = ra.w; bl = (f32x2){bflo(q), bflo(q)}; bh = (f32x2){bfhi(q), bfhi(q)};\
    ep01 = pfma(bl, wkg0[2], ep01); ep23 = pfma(bl, wkg1[2], ep23);          \
    ep45 = pfma(bl, wkg2[2], ep45); ep67 = pfma(bl, wkg3[2], ep67);          \
    ep01 = pfma(bh, wkg0[3], ep01); ep23 = pfma(bh, wkg1[3], ep23);          \
    ep45 = pfma(bh, wkg2[3], ep45); ep67 = pfma(bh, wkg3[3], ep67);          \
    q = rb.x; bl = (f32x2){bflo(q), bflo(q)}; bh = (f32x2){bfhi(q), bfhi(q)};\
    ep01 = pfma(bl, wkg0[4], ep01); ep23 = pfma(bl, wkg1[4], ep23);          \
    ep45 = pfma(bl, wkg2[4], ep45); ep67 = pfma(bl, wkg3[4], ep67);          \
    ep01 = pfma(bh, wkg0[5], ep01); ep23 = pfma(bh, wkg1[5], ep23);          \
    ep45 = pfma(bh, wkg2[5], ep45); ep67 = pfma(bh, wkg3[5], ep67);          \
    q = rb.y; bl = (f32x2){bflo(q), bflo(q)}; bh = (f32x2){bfhi(q), bfhi(q)};\
    ep01 = pfma(bl, wkg0[6], ep01); ep23 = pfma(bl, wkg1[6], ep23);          \
    ep45 = pfma(bl, wkg2[6], ep45); ep67 = pfma(bl, wkg3[6], ep67);          \
    ep01 = pfma(bh, wkg0[7], ep01); ep23 = pfma(bh, wkg1[7], ep23);          \
    ep45 = pfma(bh, wkg2[7], ep45); ep67 = pfma(bh, wkg3[7], ep67);          \
    q = rb.z; bl = (f32x2){bflo(q), bflo(q)}; bh = (f32x2){bfhi(q), bfhi(q)};\
    ep01 = pfma(bl, wkg0[8], ep01); ep23 = pfma(bl, wkg1[8], ep23);          \
    ep45 = pfma(bl, wkg2[8], ep45); ep67 = pfma(bl, wkg3[8], ep67);          \
    ep01 = pfma(bh, wkg0[9], ep01); ep23 = pfma(bh, wkg1[9], ep23);          \
    ep45 = pfma(bh, wkg2[9], ep45); ep67 = pfma(bh, wkg3[9], ep67);          \
    q = rb.w; bl = (f32x2){bflo(q), bflo(q)}; bh = (f32x2){bfhi(q), bfhi(q)};\
    ep01 = pfma(bl, wkg0[10], ep01); ep23 = pfma(bl, wkg1[10], ep23);        \
    ep45 = pfma(bl, wkg2[10], ep45); ep67 = pfma(bl, wkg3[10], ep67);        \
    ep01 = pfma(bh, wkg0[11], ep01); ep23 = pfma(bh, wkg1[11], ep23);        \
    ep45 = pfma(bh, wkg2[11], ep45); ep67 = pfma(bh, wkg3[11], ep67);        \
    f32x2 s01 = __builtin_elementwise_max(ep01, ep01 * (f32x2){0.2f, 0.2f}); \
    f32x2 s23 = __builtin_elementwise_max(ep23, ep23 * (f32x2){0.2f, 0.2f}); \
    f32x2 s45 = __builtin_elementwise_max(ep45, ep45 * (f32x2){0.2f, 0.2f}); \
    f32x2 s67 = __builtin_elementwise_max(ep67, ep67 * (f32x2){0.2f, 0.2f}); \
    f32x2 pv = s01 * at01;                                                   \
    pv = pfma(s23, at23, pv);                                                \
    pv = pfma(s45, at45, pv);                                                \
    pv = pfma(s67, at67, pv);                                                \
    float v = pv.x + pv.y;                                                   \
    RED4(v)                                                                  \
    bool ok = (OKEXPR);                                                      \
    float dm = v - m;                                                        \
    float e = __builtin_amdgcn_exp2f(-fabsf(dm));                            \
    bool big = dm > 0.f;                                                     \
    float sc = (big && ok) ? e : 1.f;                                        \
    float p = ok ? (big ? 1.f : e) : 0.f;                                    \
    m = (ok && big) ? v : m;                                                 \
    d = fmaf(d, sc, p);                                                      \
    f32x2 scv = (f32x2){sc, sc}, pvv = (f32x2){p, p};                        \
    acc01 = pfma(acc01, scv, pvv * xa01);                                    \
    acc23 = pfma(acc23, scv, pvv * xa23);                                    \
    acc45 = pfma(acc45, scv, pvv * xa45);                                    \
    acc67 = pfma(acc67, scv, pvv * xa67);                                    \
  }

__global__ __launch_bounds__(256) void gat_kernel(
    const ushort* __restrict__ xl16, const ushort* __restrict__ xr16,
    const uint* __restrict__ erec, const int* __restrict__ off,
    const float* __restrict__ Wel, const float* __restrict__ attl,
    const float* __restrict__ bol, ushort* __restrict__ out16) {
  int lane = threadIdx.x & 63;
  int node = blockIdx.x * 4 + (threadIdx.x >> 6);
  if (node >= N_NODES) return;
  int quad = lane >> 4;          // edge slot 0..3
  int c0 = (lane & 15) * 8;      // 8 channels per lane (head = 4 lanes)

  f32x2 wkg0[12], wkg1[12], wkg2[12], wkg3[12];
#pragma unroll
  for (int k = 0; k < 12; k++) {
    float4 a = *(const float4*)&Wel[k * HID + c0];
    float4 b = *(const float4*)&Wel[k * HID + c0 + 4];
    wkg0[k] = (f32x2){a.x, a.y};
    wkg1[k] = (f32x2){a.z, a.w};
    wkg2[k] = (f32x2){b.x, b.y};
    wkg3[k] = (f32x2){b.z, b.w};
  }
  float4 ata = *(const float4*)&attl[c0];
  float4 atb = *(const float4*)&attl[c0 + 4];
  f32x2 at01 = (f32x2){ata.x * LOG2E, ata.y * LOG2E};
  f32x2 at23 = (f32x2){ata.z * LOG2E, ata.w * LOG2E};
  f32x2 at45 = (f32x2){atb.x * LOG2E, atb.y * LOG2E};
  f32x2 at67 = (f32x2){atb.z * LOG2E, atb.w * LOG2E};
  uint4 xru = *(const uint4*)&xr16[((uint)node << 7) + c0];
  f32x2 xr01 = (f32x2){bflo(xru.x), bfhi(xru.x)};
  f32x2 xr23 = (f32x2){bflo(xru.y), bfhi(xru.y)};
  f32x2 xr45 = (f32x2){bflo(xru.z), bfhi(xru.z)};
  f32x2 xr67 = (f32x2){bflo(xru.w), bfhi(xru.w)};

  int is = off[node], deg = off[node + 1] - is;

  float m = -INFINITY, d = 0.f;
  f32x2 acc01 = (f32x2){0.f, 0.f};
  f32x2 acc23 = (f32x2){0.f, 0.f};
  f32x2 acc45 = (f32x2){0.f, 0.f};
  f32x2 acc67 = (f32x2){0.f, 0.f};

  if (deg > 0) {
    // clamp prologue index so quads beyond deg don't fetch stray rows
    int first = is + ((quad < deg) ? quad : 0);
    const uint* pe = erec + (size_t)first * 8;
    uint4 Ra = *(const uint4*)pe, Rb = *(const uint4*)(pe + 4);
    uint4 xw = *(const uint4*)&xl16[(Ra.x << 7) + c0];
    int full = deg >> 2;
    for (int i = 0; i < full; i++) {
      const uint* pn = pe + 32;                         // next record for this quad
      uint4 Na = *(const uint4*)pn, Nb = *(const uint4*)(pn + 4);
      uint4 xn = *(const uint4*)&xl16[(Na.x << 7) + c0];
      GAT_EDGE8(Ra, Rb, xw, true)
      Ra = Na; Rb = Nb; xw = xn; pe = pn;
    }
    if (deg & 3) GAT_EDGE8(Ra, Rb, xw, quad < (deg & 3))
  }

  // merge the 4 quad-chains (same channels live in lanes l^16, l^32)
#pragma unroll
  for (int ofs = 16; ofs <= 32; ofs <<= 1) {
    float mo = __shfl_xor(m, ofs);
    float dd = __shfl_xor(d, ofs);
    f32x2 o01, o23, o45, o67;
    o01.x = __shfl_xor(acc01.x, ofs); o01.y = __shfl_xor(acc01.y, ofs);
    o23.x = __shfl_xor(acc23.x, ofs); o23.y = __shfl_xor(acc23.y, ofs);
    o45.x = __shfl_xor(acc45.x, ofs); o45.y = __shfl_xor(acc45.y, ofs);
    o67.x = __shfl_xor(acc67.x, ofs); o67.y = __shfl_xor(acc67.y, ofs);
    float mn = fmaxf(m, mo);
    float wS = (m > -INFINITY) ? __builtin_amdgcn_exp2f(m - mn) : 0.f;
    float wO = (mo > -INFINITY) ? __builtin_amdgcn_exp2f(mo - mn) : 0.f;
    d = d * wS + dd * wO;
    f32x2 wSv = (f32x2){wS, wS}, wOv = (f32x2){wO, wO};
    acc01 = acc01 * wSv + o01 * wOv;
    acc23 = acc23 * wSv + o23 * wOv;
    acc45 = acc45 * wSv + o45 * wOv;
    acc67 = acc67 * wSv + o67 * wOv;
    m = mn;
  }
  float inv = 1.f / (d + 1e-16f);
  if ((lane & 48) == 0) {   // lanes 0-15 of the wave
    float4 boa = *(const float4*)&bol[c0];
    float4 bob = *(const float4*)&bol[c0 + 4];
    uint4 o;
    o.x = pk_bf16(fmaf(acc01.x, inv, boa.x), fmaf(acc01.y, inv, boa.y));
    o.y = pk_bf16(fmaf(acc23.x, inv, boa.z), fmaf(acc23.y, inv, boa.w));
    o.z = pk_bf16(fmaf(acc45.x, inv, bob.x), fmaf(acc45.y, inv, bob.y));
    o.w = pk_bf16(fmaf(acc67.x, inv, bob.z), fmaf(acc67.y, inv, bob.w));
    *(uint4*)&out16[((uint)node << 7) + c0] = o;
  }
}

// ---------------- BatchNorm stats (bf16 input) ----------------
__global__ void bnstats_kernel(const ushort* __restrict__ t16, float* __restrict__ sums) {
  int tid = threadIdx.x;
  int c2 = (tid & 63) * 2;     // channel pair
  int grp = tid >> 6;          // 0..3 row groups
  float s0 = 0.f, s1 = 0.f, q0 = 0.f, q1 = 0.f;
  for (int n = blockIdx.x * 4 + grp; n < N_NODES; n += 1024) {
    uint v = *(const uint*)&t16[((uint)n << 7) + c2];
    float a = bflo(v), b = bfhi(v);
    s0 += a; q0 = fmaf(a, a, q0);
    s1 += b; q1 = fmaf(b, b, q1);
  }
  __shared__ float ls[4][128], lq[4][128];
  *(float2*)&ls[grp][c2] = make_float2(s0, s1);
  *(float2*)&lq[grp][c2] = make_float2(q0, q1);
  __syncthreads();
  if (tid < 128) {
    float s = ls[0][tid] + ls[1][tid] + ls[2][tid] + ls[3][tid];
    atomicAdd(&sums[tid], s);
    float q = lq[0][tid] + lq[1][tid] + lq[2][tid] + lq[3][tid];
    atomicAdd(&sums[128 + tid], q);
  }
}

// ---------------- policy head (one edge per 16 lanes, grid-stride) ----------------
__global__ __launch_bounds__(256) void policy_kernel(
    const ushort* __restrict__ Ps, const ushort* __restrict__ Pd,
    const int* __restrict__ src, const int* __restrict__ dst,
    const float* __restrict__ edge_attr, const float* __restrict__ Wp1e,
    const float* __restrict__ bp1, const float* __restrict__ Wp2,
    const float* __restrict__ bp2, float* __restrict__ outp) {
  int j = threadIdx.x & 15;
  int gid = (blockIdx.x * 256 + threadIdx.x) >> 4;
  int ngroups = (gridDim.x * 256) >> 4;
  float4 we[12];
#pragma unroll
  for (int k = 0; k < 12; k++) we[k] = *(const float4*)&Wp1e[k * 64 + j * 4];
  float4 b4 = *(const float4*)&bp1[j * 4];
  float4 w2 = *(const float4*)&Wp2[j * 4];
  float bp2c = bp2[0];
  for (int e = gid; e < N_EDGES; e += ngroups) {
    int s = src[e], d = dst[e];
    const float* eap = &edge_attr[(size_t)e * EDIM];
    float4 e0 = *(const float4*)eap;
    float4 e1 = *(const float4*)(eap + 4);
    float4 e2 = *(const float4*)(eap + 8);
    uint2 psu = *(const uint2*)&Ps[(size_t)s * 64 + j * 4];
    uint2 pdu = *(const uint2*)&Pd[(size_t)d * 64 + j * 4];
    float eav[12] = {e0.x, e0.y, e0.z, e0.w, e1.x, e1.y, e1.z, e1.w, e2.x, e2.y, e2.z, e2.w};
    float hx = bflo(psu.x) + bflo(pdu.x) + b4.x;
    float hy = bfhi(psu.x) + bfhi(pdu.x) + b4.y;
    float hz = bflo(psu.y) + bflo(pdu.y) + b4.z;
    float hw = bfhi(psu.y) + bfhi(pdu.y) + b4.w;
#pragma unroll
    for (int k = 0; k < 12; k++) {
      hx = fmaf(eav[k], we[k].x, hx);
      hy = fmaf(eav[k], we[k].y, hy);
      hz = fmaf(eav[k], we[k].z, hz);
      hw = fmaf(eav[k], we[k].w, hw);
    }
    hx = fmaxf(hx, 0.f); hy = fmaxf(hy, 0.f); hz = fmaxf(hz, 0.f); hw = fmaxf(hw, 0.f);
    float v = fmaf(hx, w2.x, fmaf(hy, w2.y, fmaf(hz, w2.z, hw * w2.w)));
    v += __shfl_xor(v, 1);
    v += __shfl_xor(v, 2);
    v += __shfl_xor(v, 4);
    v += __shfl_xor(v, 8);
    if (j == 0) outp[e] = v + bp2c;
  }
}

// ---------------- pooled mean + value head ----------------
__device__ int lower_bound_dev(const int* a, int n, int key) {
  int lo = 0, hi = n;
  while (lo < hi) {
    int mid = (lo + hi) >> 1;
    if (a[mid] < key) lo = mid + 1; else hi = mid;
  }
  return lo;
}

__global__ void poolvalue_kernel(const float* __restrict__ h, const int* __restrict__ batch,
                                 const float* __restrict__ Wv1, const float* __restrict__ bv1,
                                 const float* __restrict__ Wv2, const float* __restrict__ bv2,
                                 float* __restrict__ outv) {
  __shared__ float pl[128];
  __shared__ float hd[64];
  __shared__ int range[2];
  int g = blockIdx.x, t = threadIdx.x;
  if (t == 0) {
    range[0] = lower_bound_dev(batch, N_NODES, g);
    range[1] = lower_bound_dev(batch, N_NODES, g + 1);
  }
  __syncthreads();
  int lo = range[0], hi = range[1];
  float s = 0.f;
  for (int n = lo; n < hi; n++) s += h[(size_t)n * HID + t];
  float cnt = (float)(hi - lo);
  pl[t] = s / fmaxf(cnt, 1.f);
  __syncthreads();
  if (t < 64) {
    float a = bv1[t];
    for (int c = 0; c < 128; c++) a = fmaf(pl[c], Wv1[c * 64 + t], a);
    hd[t] = fmaxf(a, 0.f);
  }
  __syncthreads();
  if (t < 3) {
    float a = bv2[t];
    for (int j = 0; j < 64; j++) a = fmaf(hd[j], Wv2[j * 3 + t], a);
    outv[g * 3 + t] = a;
  }
}

// ---------------- host ----------------
extern "C" void kernel_launch(void* const* d_in, const int* in_sizes, int n_in,
                              void* d_out, int out_size, void* d_ws, size_t ws_size,
                              hipStream_t stream) {
  (void)in_sizes; (void)n_in; (void)out_size; (void)ws_size;
  const float* x    = (const float*)d_in[0];
  const int*   src  = (const int*)d_in[1];
  const int*   dst  = (const int*)d_in[2];
  const int*   batch= (const int*)d_in[3];
  const float* ea   = (const float*)d_in[4];
  const float* Win  = (const float*)d_in[5];
  const float* b_in = (const float*)d_in[6];
  const float* Wl   = (const float*)d_in[7];
  const float* bl   = (const float*)d_in[8];
  const float* Wr   = (const float*)d_in[9];
  const float* br   = (const float*)d_in[10];
  const float* We   = (const float*)d_in[11];
  const float* att  = (const float*)d_in[12];
  const float* bo   = (const float*)d_in[13];
  const float* gamma= (const float*)d_in[14];
  const float* beta = (const float*)d_in[15];
  const float* Wv1  = (const float*)d_in[16];
  const float* bv1  = (const float*)d_in[17];
  const float* Wv2  = (const float*)d_in[18];
  const float* bv2  = (const float*)d_in[19];
  const float* Wp1  = (const float*)d_in[20];
  const float* bp1  = (const float*)d_in[21];
  const float* Wp2  = (const float*)d_in[22];
  const float* bp2  = (const float*)d_in[23];

  float* outv = (float*)d_out;                      // [G,3]
  float* outp = outv + (size_t)N_GRAPHS * 3;        // [E]

  float* hres   = (float*)d_ws;                           // residual / final h (f32)
  ushort* tmp16 = (ushort*)(hres + (size_t)N_NODES * HID); // gat output (bf16)
  ushort* h16   = tmp16 + (size_t)N_NODES * HID;           // inproj bf16
  ushort* xl16  = h16 + (size_t)N_NODES * HID;
  ushort* xr16  = xl16 + (size_t)N_NODES * HID;
  float* stats  = (float*)(xr16 + (size_t)N_NODES * HID);
  ushort* wpk   = (ushort*)(stats + NLAYERS * 256);
  ushort* wppk  = wpk + (size_t)NLAYERS * 4 * 256 * 32;
  int* off    = (int*)(wppk + 4 * 128 * 32);
  int* cursor = off + (N_NODES + 1);
  int* bsum   = cursor + N_NODES;
  uint* erec  = (uint*)(((uintptr_t)(bsum + 256) + 15) & ~(uintptr_t)15);

  const int NB = (N_NODES + 255) / 256;
  const int EB = (N_EDGES + 255) / 256;

  zero_kernel<<<NB, 256, 0, stream>>>(off, cursor, stats, erec);
  count_kernel<<<EB, 256, 0, stream>>>(dst, off);
  scan1_kernel<<<NB, 256, 0, stream>>>(off, bsum);
  scan2_kernel<<<1, 256, 0, stream>>>(bsum, NB);
  scan3_kernel<<<NB, 256, 0, stream>>>(off, bsum);
  scatter_kernel<<<EB, 256, 0, stream>>>(src, dst, ea, off, cursor, erec);
  wprep_kernel<<<(NLAYERS * 4 * 256 * 32 + 255) / 256, 256, 0, stream>>>(Wl, Wr, wpk);
  wprep_pol_kernel<<<(4 * 128 * 32 + 255) / 256, 256, 0, stream>>>(Wp1, wppk);
  inproj_kernel<<<N_NODES / 2, 256, 0, stream>>>(x, Win, b_in, hres, h16);

  const int MB = (N_NODES + 63) / 64;
  const int GATB = (N_NODES + 3) / 4;

  for (int l = 0; l < NLAYERS; l++) {
    if (l == 0) {
      gemm_mfma_kernel<256, 128, true, true, false, false, false><<<MB, 256, 0, stream>>>(
          h16, nullptr, nullptr, nullptr, nullptr, nullptr, nullptr,
          wpk, bl, br, xl16, xr16, N_NODES);
    } else if (l & 1) {
      int p = l - 1;
      gemm_mfma_kernel<256, 128, true, true, true, false, false><<<MB, 256, 0, stream>>>(
          nullptr, tmp16, stats + p * 256, gamma + p * HID, beta + p * HID, nullptr, nullptr,
          wpk + (size_t)l * 32768, bl + l * HID, br + l * HID, xl16, xr16, N_NODES);
    } else {
      int p = l - 1;
      gemm_mfma_kernel<256, 128, true, true, true, true, true><<<MB, 256, 0, stream>>>(
          nullptr, tmp16, stats + p * 256, gamma + p * HID, beta + p * HID, hres, hres,
          wpk + (size_t)l * 32768, bl + l * HID, br + l * HID, xl16, xr16, N_NODES);
    }
    gat_kernel<<<GATB, 256, 0, stream>>>(xl16, xr16, erec, off,
                                         We + (size_t)l * EDIM * HID, att + (size_t)l * HID,
                                         bo + (size_t)l * HID, tmp16);
    bnstats_kernel<<<256, 256, 0, stream>>>(tmp16, stats + l * 256);
  }

  // policy projections: BN of layer 7 fused (+residual, final h -> hres), bf16 out
  ushort* Ps = xl16;
  ushort* Pd = xr16;
  gemm_mfma_kernel<128, 64, false, true, true, true, true><<<MB, 256, 0, stream>>>(
      nullptr, tmp16, stats + 7 * 256, gamma + 7 * HID, beta + 7 * HID, hres, hres,
      wppk, nullptr, nullptr, Ps, Pd, N_NODES);
  policy_kernel<<<2048, 256, 0, stream>>>(Ps, Pd, src, dst, ea,
                                          Wp1 + 256 * 64, bp1, Wp2, bp2, outp);
  poolvalue_kernel<<<N_GRAPHS, 128, 0, stream>>>(hres, batch, Wv1, bv1, Wv2, bv2, outv);
}

// Round 15
// 1153.340 us; speedup vs baseline: 2.6368x; 1.3034x over previous
//
#include <hip/hip_runtime.h>
#include <math.h>

#define N_NODES 50000
#define N_EDGES 500000
#define N_GRAPHS 2048
#define HID 128
#define EDIM 12
#define NLAYERS 8
#define EPS_BN 1e-5f
#define LOG2E 1.44269504088896340736f
#define GAT_BLOCKS 2048
#define GAT_WAVES (GAT_BLOCKS * 4)

typedef __attribute__((ext_vector_type(8))) short short8;
typedef __attribute__((ext_vector_type(4))) float f32x4;
typedef __attribute__((ext_vector_type(2))) float f32x2;
typedef unsigned int uint;
typedef unsigned short ushort;

__device__ inline ushort f2bf(float x) {
  unsigned u = __float_as_uint(x);
  u = (u + 0x7FFFu + ((u >> 16) & 1u)) >> 16;  // RNE
  return (ushort)u;
}
__device__ inline unsigned pk_bf16(float a, float b) {
  return (unsigned)f2bf(a) | ((unsigned)f2bf(b) << 16);
}
__device__ inline float bflo(uint q) { return __uint_as_float(q << 16); }
__device__ inline float bfhi(uint q) { return __uint_as_float(q & 0xFFFF0000u); }
__device__ inline f32x2 pfma(f32x2 a, f32x2 b, f32x2 c) {
  return __builtin_elementwise_fma(a, b, c);
}
// butterfly add, pure-VALU DPP (ctrl must be a literal)
template <int CTRL>
__device__ inline float dpp_add(float v) {
  int s = __builtin_amdgcn_update_dpp(0, __float_as_int(v), CTRL, 0xF, 0xF, true);
  return v + __int_as_float(s);
}
// 8-lane butterfly (head = 8 lanes x 4ch): xor1, xor2, mirror-within-8
#define RED8(v)               \
  v = dpp_add<0xB1>(v);       \
  v = dpp_add<0x4E>(v);       \
  v = dpp_add<0x141>(v);

// ---------------- CSR build ----------------
__global__ void zero_kernel(int* deg, int* cursor, float* stats, uint* erec) {
  int i = blockIdx.x * 256 + threadIdx.x;
  if (i < N_NODES) { deg[i] = 0; cursor[i] = 0; }
  if (i < NLAYERS * 256) stats[i] = 0.f;
  if (i < 32) erec[(size_t)N_EDGES * 8 + i] = 0u;  // 4 pad records (src=0)
}

__global__ void count_kernel(const int* __restrict__ dst, int* __restrict__ deg) {
  int e = blockIdx.x * 256 + threadIdx.x;
  if (e < N_EDGES) atomicAdd(&deg[dst[e]], 1);
}

__global__ void scan1_kernel(int* __restrict__ off, int* __restrict__ bsum) {
  __shared__ int s[256];
  int t = threadIdx.x; int n = blockIdx.x * 256 + t;
  int x = (n < N_NODES) ? off[n] : 0;
  s[t] = x; __syncthreads();
  for (int o = 1; o < 256; o <<= 1) {
    int v = (t >= o) ? s[t - o] : 0;
    __syncthreads(); s[t] += v; __syncthreads();
  }
  if (n < N_NODES) off[n] = s[t] - x;
  if (t == 255) bsum[blockIdx.x] = s[255];
}

__global__ void scan2_kernel(int* __restrict__ bsum, int nb) {
  __shared__ int s[256];
  int t = threadIdx.x;
  int x = (t < nb) ? bsum[t] : 0;
  s[t] = x; __syncthreads();
  for (int o = 1; o < 256; o <<= 1) {
    int v = (t >= o) ? s[t - o] : 0;
    __syncthreads(); s[t] += v; __syncthreads();
  }
  if (t < nb) bsum[t] = s[t] - x;
}

__global__ void scan3_kernel(int* __restrict__ off, const int* __restrict__ bsum) {
  int t = threadIdx.x; int n = blockIdx.x * 256 + t;
  if (n < N_NODES) off[n] += bsum[blockIdx.x];
  if (n == 0 && blockIdx.x == 0) off[N_NODES] = N_EDGES;
}

// erec[pos] = {src, pad, ea_bf16 x6} (8 dwords, 32B)
__global__ void scatter_kernel(const int* __restrict__ src, const int* __restrict__ dst,
                               const float* __restrict__ ea,
                               const int* __restrict__ off, int* __restrict__ cursor,
                               uint* __restrict__ erec) {
  int e = blockIdx.x * 256 + threadIdx.x;
  if (e < N_EDGES) {
    int d = dst[e];
    int p = atomicAdd(&cursor[d], 1);
    int pos = off[d] + p;
    const float* eap = &ea[(size_t)e * EDIM];
    float4 e0 = *(const float4*)eap;
    float4 e1 = *(const float4*)(eap + 4);
    float4 e2 = *(const float4*)(eap + 8);
    uint4 q0, q1;
    q0.x = (uint)src[e]; q0.y = 0u;
    q0.z = pk_bf16(e0.x, e0.y); q0.w = pk_bf16(e0.z, e0.w);
    q1.x = pk_bf16(e1.x, e1.y); q1.y = pk_bf16(e1.z, e1.w);
    q1.z = pk_bf16(e2.x, e2.y); q1.w = pk_bf16(e2.z, e2.w);
    uint* o = &erec[(size_t)pos * 8];
    *(uint4*)o = q0;
    *(uint4*)(o + 4) = q1;
  }
}

// ---------------- weight packing for MFMA fragments ----------------
__global__ void wprep_kernel(const float* __restrict__ Wl, const float* __restrict__ Wr,
                             ushort* __restrict__ wpk) {
  int idx = blockIdx.x * 256 + threadIdx.x;
  if (idx >= NLAYERS * 4 * 256 * 32) return;
  int kk = idx & 31;
  int cc = (idx >> 5) & 255;
  int kb = (idx >> 13) & 3;
  int layer = idx >> 15;
  int k = kb * 32 + kk;
  float v = (cc < 128) ? Wl[((size_t)layer * 128 + k) * 128 + cc]
                       : Wr[((size_t)layer * 128 + k) * 128 + (cc - 128)];
  wpk[idx] = f2bf(v);
}

__global__ void wprep_pol_kernel(const float* __restrict__ Wp1, ushort* __restrict__ wppk) {
  int idx = blockIdx.x * 256 + threadIdx.x;
  if (idx >= 4 * 128 * 32) return;
  int kk = idx & 31;
  int cc = (idx >> 5) & 127;
  int kb = idx >> 12;
  int k = kb * 32 + kk;
  float v = (cc < 64) ? Wp1[(size_t)k * 64 + cc] : Wp1[(size_t)(128 + k) * 64 + (cc - 64)];
  wppk[idx] = f2bf(v);
}

// ---------------- input projection (writes f32 hres + bf16 h16) ----------------
__global__ void inproj_kernel(const float* __restrict__ x, const float* __restrict__ Win,
                              const float* __restrict__ b_in, float* __restrict__ h,
                              ushort* __restrict__ h16) {
  __shared__ float xs[44];
  int t = threadIdx.x;
  int n0 = blockIdx.x * 2;
  if (t < 44) xs[t] = x[n0 * 22 + t];
  __syncthreads();
  int c = t & 127, half = t >> 7;
  int n = n0 + half;
  if (n < N_NODES) {
    float acc = b_in[c];
#pragma unroll
    for (int k = 0; k < 22; k++) acc = fmaf(xs[half * 22 + k], Win[k * HID + c], acc);
    float v = fmaxf(acc, 0.f);
    h[(size_t)n * HID + c] = v;
    h16[(size_t)n * HID + c] = f2bf(v);
  }
}

// ---------------- MFMA GEMM (optionally BN+residual+relu fused on input) --------
template <int NOUT, int SPLIT, bool BIAS, bool OUTBF16, bool BNFUSE, bool RESID, bool WRITEH>
__global__ __launch_bounds__(256) void gemm_mfma_kernel(
    const ushort* __restrict__ A16, const ushort* __restrict__ T16,
    const float* __restrict__ stats, const float* __restrict__ gamma,
    const float* __restrict__ beta, const float* __restrict__ res,
    float* __restrict__ hout,
    const ushort* __restrict__ Wpk, const float* __restrict__ b1,
    const float* __restrict__ b2, void* __restrict__ C1v, void* __restrict__ C2v,
    int nrows) {
  __shared__ ushort As[64][136];  // +8 pad
  int t = threadIdx.x;
  int brow = blockIdx.x * 64;
  if constexpr (!BNFUSE) {
#pragma unroll
    for (int i = 0; i < 4; i++) {
      int f = t + i * 256;
      int r = f >> 4, cg = (f & 15) * 8;
      int g = brow + r;
      uint4 v = make_uint4(0, 0, 0, 0);
      if (g < nrows) v = *(const uint4*)&A16[(size_t)g * HID + cg];
      *(uint4*)&As[r][cg] = v;
    }
  } else {
    int cg = (t & 31) * 4;
    int r0 = t >> 5;
    const float invN = 1.f / (float)N_NODES;
    float4 sm = *(const float4*)&stats[cg];
    float4 sq = *(const float4*)&stats[128 + cg];
    float4 gm = *(const float4*)&gamma[cg];
    float4 bt = *(const float4*)&beta[cg];
    float s4[4] = {sm.x, sm.y, sm.z, sm.w};
    float q4[4] = {sq.x, sq.y, sq.z, sq.w};
    float g4[4] = {gm.x, gm.y, gm.z, gm.w};
    float bb4[4] = {bt.x, bt.y, bt.z, bt.w};
    float scl[4], shf[4];
#pragma unroll
    for (int k = 0; k < 4; k++) {
      float mu = s4[k] * invN;
      float var = q4[k] * invN - mu * mu;
      float rs = rsqrtf(var + EPS_BN);
      scl[k] = g4[k] * rs;
      shf[k] = bb4[k] - mu * scl[k];
    }
#pragma unroll
    for (int rr = 0; rr < 8; rr++) {
      int r = r0 + rr * 8;
      int g = brow + r;
      uint2 tvu = make_uint2(0u, 0u);
      if (g < nrows) tvu = *(const uint2*)&T16[(size_t)g * HID + cg];
      float o0 = fmaf(bflo(tvu.x), scl[0], shf[0]);
      float o1 = fmaf(bfhi(tvu.x), scl[1], shf[1]);
      float o2 = fmaf(bflo(tvu.y), scl[2], shf[2]);
      float o3 = fmaf(bfhi(tvu.y), scl[3], shf[3]);
      if constexpr (RESID) {
        if (g < nrows) {
          float4 rv = *(const float4*)&res[(size_t)g * HID + cg];
          o0 += rv.x; o1 += rv.y; o2 += rv.z; o3 += rv.w;
        }
      }
      o0 = fmaxf(o0, 0.f); o1 = fmaxf(o1, 0.f);
      o2 = fmaxf(o2, 0.f); o3 = fmaxf(o3, 0.f);
      if constexpr (WRITEH) {
        if (g < nrows) {
          float4 ov = make_float4(o0, o1, o2, o3);
          *(float4*)&hout[(size_t)g * HID + cg] = ov;
        }
      }
      *(uint2*)&As[r][cg] = make_uint2(pk_bf16(o0, o1), pk_bf16(o2, o3));
    }
  }
  __syncthreads();
  int lane = t & 63, wave = t >> 6;
  int arow = wave * 16 + (lane & 15);
  int k8 = (lane >> 4) * 8;
  constexpr int NT = NOUT / 16;
  f32x4 acc[NT];
#pragma unroll
  for (int n = 0; n < NT; n++) acc[n] = (f32x4){0.f, 0.f, 0.f, 0.f};
#pragma unroll
  for (int kb = 0; kb < 4; kb++) {
    short8 a = *(const short8*)&As[arow][kb * 32 + k8];
#pragma unroll
    for (int n = 0; n < NT; n++) {
      int col = n * 16 + (lane & 15);
      short8 b = *(const short8*)&Wpk[((size_t)(kb * NOUT + col)) * 32 + k8];
      acc[n] = __builtin_amdgcn_mfma_f32_16x16x32_bf16(a, b, acc[n], 0, 0, 0);
    }
  }
  // C/D: col = lane&15, row = (lane>>4)*4 + j
  int rbase = brow + wave * 16 + (lane >> 4) * 4;
  int ccol = lane & 15;
#pragma unroll
  for (int n = 0; n < NT; n++) {
    int col = n * 16 + ccol;
    float bias = 0.f;
    if (BIAS) bias = (col < SPLIT) ? b1[col] : b2[col - SPLIT];
    int colw = (col < SPLIT) ? col : col - SPLIT;
#pragma unroll
    for (int j = 0; j < 4; j++) {
      int row = rbase + j;
      if (row < nrows) {
        float v = acc[n][j] + bias;
        if (OUTBF16) {
          ushort* dstp = (ushort*)((col < SPLIT) ? C1v : C2v);
          dstp[(size_t)row * SPLIT + colw] = f2bf(v);
        } else {
          float* dstp = (float*)((col < SPLIT) ? C1v : C2v);
          dstp[(size_t)row * SPLIT + colw] = v;
        }
      }
    }
  }
}

// ---------------- GATv2 aggregation ----------------
// PERSISTENT waves: 2048 blocks x 4 waves = 8192 waves (full residency); each
// wave strides over nodes, layer constants (We cols, att, bo) hoisted into regs.
// Per node: 2 EDGES/wave (lanes 0-31 even, 32-63 odd; 4 ch/lane), independent
// online-softmax per half-wave merged via shfl_xor(32). 8-lane DPP head-reduce.
#define GAT_EDGE4(ra, rb, xw, OKEXPR)                                        \
  {                                                                          \
    f32x2 xa01 = (f32x2){bflo(xw.x), bfhi(xw.x)};                            \
    f32x2 xa23 = (f32x2){bflo(xw.y), bfhi(xw.y)};                            \
    f32x2 ep01 = xa01 + xr01;                                                \
    f32x2 ep23 = xa23 + xr23;                                                \
    uint q; float lo, hi;                                                    \
    q = ra.z; lo = bflo(q); hi = bfhi(q);                                    \
    ep01 = pfma((f32x2){lo, lo}, wk01[0], ep01);                             \
    ep23 = pfma((f32x2){lo, lo}, wk23[0], ep23);                             \
    ep01 = pfma((f32x2){hi, hi}, wk01[1], ep01);                             \
    ep23 = pfma((f32x2){hi, hi}, wk23[1], ep23);                             \
    q = ra.w; lo = bflo(q); hi = bfhi(q);                                    \
    ep01 = pfma((f32x2){lo, lo}, wk01[2], ep01);                             \
    ep23 = pfma((f32x2){lo, lo}, wk23[2], ep23);                             \
    ep01 = pfma((f32x2){hi, hi}, wk01[3], ep01);                             \
    ep23 = pfma((f32x2){hi, hi}, wk23[3], ep23);                             \
    q = rb.x; lo = bflo(q); hi = bfhi(q);                                    \
    ep01 = pfma((f32x2){lo, lo}, wk01[4], ep01);                             \
    ep23 = pfma((f32x2){lo, lo}, wk23[4], ep23);                             \
    ep01 = pfma((f32x2){hi, hi}, wk01[5], ep01);                             \
    ep23 = pfma((f32x2){hi, hi}, wk23[5], ep23);                             \
    q = rb.y; lo = bflo(q); hi = bfhi(q);                                    \
    ep01 = pfma((f32x2){lo, lo}, wk01[6], ep01);                             \
    ep23 = pfma((f32x2){lo, lo}, wk23[6], ep23);                             \
    ep01 = pfma((f32x2){hi, hi}, wk01[7], ep01);                             \
    ep23 = pfma((f32x2){hi, hi}, wk23[7], ep23);                             \
    q = rb.z; lo = bflo(q); hi = bfhi(q);                                    \
    ep01 = pfma((f32x2){lo, lo}, wk01[8], ep01);                             \
    ep23 = pfma((f32x2){lo, lo}, wk23[8], ep23);                             \
    ep01 = pfma((f32x2){hi, hi}, wk01[9], ep01);                             \
    ep23 = pfma((f32x2){hi, hi}, wk23[9], ep23);                             \
    q = rb.w; lo = bflo(q); hi = bfhi(q);                                    \
    ep01 = pfma((f32x2){lo, lo}, wk01[10], ep01);                            \
    ep23 = pfma((f32x2){lo, lo}, wk23[10], ep23);                            \
    ep01 = pfma((f32x2){hi, hi}, wk01[11], ep01);                            \
    ep23 = pfma((f32x2){hi, hi}, wk23[11], ep23);                            \
    f32x2 s01 = __builtin_elementwise_max(ep01, ep01 * (f32x2){0.2f, 0.2f}); \
    f32x2 s23 = __builtin_elementwise_max(ep23, ep23 * (f32x2){0.2f, 0.2f}); \
    float v = fmaf(s01.x, at4.x,                                             \
              fmaf(s01.y, at4.y, fmaf(s23.x, at4.z, s23.y * at4.w)));        \
    RED8(v)                                                                  \
    bool ok = (OKEXPR);                                                      \
    float dm = v - m;                                                        \
    float e = __builtin_amdgcn_exp2f(-fabsf(dm));                            \
    bool big = dm > 0.f;                                                     \
    float sc = (big && ok) ? e : 1.f;                                        \
    float p = ok ? (big ? 1.f : e) : 0.f;                                    \
    m = (ok && big) ? v : m;                                                 \
    d = fmaf(d, sc, p);                                                      \
    acc01 = pfma(acc01, (f32x2){sc, sc}, (f32x2){p, p} * xa01);              \
    acc23 = pfma(acc23, (f32x2){sc, sc}, (f32x2){p, p} * xa23);              \
  }

__global__ __launch_bounds__(256) void gat_kernel(
    const ushort* __restrict__ xl16, const ushort* __restrict__ xr16,
    const uint* __restrict__ erec, const int* __restrict__ off,
    const float* __restrict__ Wel, const float* __restrict__ attl,
    const float* __restrict__ bol, ushort* __restrict__ out16) {
  int lane = threadIdx.x & 63;
  int gwave = blockIdx.x * 4 + (threadIdx.x >> 6);
  int half = lane >> 5;          // 0: even edges, 1: odd edges
  int c0 = (lane & 31) * 4;      // 4 channels per lane (head = c0/32 spans 8 lanes)

  // layer constants: loaded ONCE per wave, live across all its nodes
  f32x2 wk01[12], wk23[12];
#pragma unroll
  for (int k = 0; k < 12; k++) {
    float4 w = *(const float4*)&Wel[k * HID + c0];
    wk01[k] = (f32x2){w.x, w.y};
    wk23[k] = (f32x2){w.z, w.w};
  }
  float4 at4 = *(const float4*)&attl[c0];
  at4.x *= LOG2E; at4.y *= LOG2E; at4.z *= LOG2E; at4.w *= LOG2E;
  float4 bo = *(const float4*)&bol[c0];

  for (int node = gwave; node < N_NODES; node += GAT_WAVES) {
    uint2 xru = *(const uint2*)&xr16[((uint)node << 7) + c0];
    f32x2 xr01 = (f32x2){bflo(xru.x), bfhi(xru.x)};
    f32x2 xr23 = (f32x2){bflo(xru.y), bfhi(xru.y)};

    int is = off[node], deg = off[node + 1] - is;

    float m = -INFINITY, d = 0.f;
    f32x2 acc01 = (f32x2){0.f, 0.f};
    f32x2 acc23 = (f32x2){0.f, 0.f};

    if (deg > 0) {
      const uint* pe = erec + ((size_t)is + half) * 8;   // this half's first record
      uint4 Ra = *(const uint4*)pe, Rb = *(const uint4*)(pe + 4);
      uint2 xw = *(const uint2*)&xl16[(Ra.x << 7) + c0];
      int full = deg >> 1;
      for (int i = 0; i < full; i++) {
        const uint* pn = pe + 16;                         // next record for this half
        uint4 Na = *(const uint4*)pn, Nb = *(const uint4*)(pn + 4);
        uint2 xn = *(const uint2*)&xl16[(Na.x << 7) + c0];
        GAT_EDGE4(Ra, Rb, xw, true)
        Ra = Na; Rb = Nb; xw = xn; pe = pn;
      }
      if (deg & 1) GAT_EDGE4(Ra, Rb, xw, half == 0)
    }

    // merge the two half-wave chains (same channels live in lane l and l^32)
    float mo = __shfl_xor(m, 32);
    float dd = __shfl_xor(d, 32);
    f32x2 o01, o23;
    o01.x = __shfl_xor(acc01.x, 32); o01.y = __shfl_xor(acc01.y, 32);
    o23.x = __shfl_xor(acc23.x, 32); o23.y = __shfl_xor(acc23.y, 32);
    float mn = fmaxf(m, mo);
    float wS = (m > -INFINITY) ? __builtin_amdgcn_exp2f(m - mn) : 0.f;
    float wO = (mo > -INFINITY) ? __builtin_amdgcn_exp2f(mo - mn) : 0.f;
    float den = d * wS + dd * wO;
    f32x2 a01 = acc01 * (f32x2){wS, wS} + o01 * (f32x2){wO, wO};
    f32x2 a23 = acc23 * (f32x2){wS, wS} + o23 * (f32x2){wO, wO};
    float inv = 1.f / (den + 1e-16f);
    if (half == 0) {
      uint2 o;
      o.x = pk_bf16(fmaf(a01.x, inv, bo.x), fmaf(a01.y, inv, bo.y));
      o.y = pk_bf16(fmaf(a23.x, inv, bo.z), fmaf(a23.y, inv, bo.w));
      *(uint2*)&out16[((uint)node << 7) + c0] = o;
    }
  }
}

// ---------------- BatchNorm stats (bf16 input) ----------------
__global__ void bnstats_kernel(const ushort* __restrict__ t16, float* __restrict__ sums) {
  int tid = threadIdx.x;
  int c2 = (tid & 63) * 2;     // channel pair
  int grp = tid >> 6;          // 0..3 row groups
  float s0 = 0.f, s1 = 0.f, q0 = 0.f, q1 = 0.f;
  for (int n = blockIdx.x * 4 + grp; n < N_NODES; n += 1024) {
    uint v = *(const uint*)&t16[((uint)n << 7) + c2];
    float a = bflo(v), b = bfhi(v);
    s0 += a; q0 = fmaf(a, a, q0);
    s1 += b; q1 = fmaf(b, b, q1);
  }
  __shared__ float ls[4][128], lq[4][128];
  *(float2*)&ls[grp][c2] = make_float2(s0, s1);
  *(float2*)&lq[grp][c2] = make_float2(q0, q1);
  __syncthreads();
  if (tid < 128) {
    float s = ls[0][tid] + ls[1][tid] + ls[2][tid] + ls[3][tid];
    atomicAdd(&sums[tid], s);
    float q = lq[0][tid] + lq[1][tid] + lq[2][tid] + lq[3][tid];
    atomicAdd(&sums[128 + tid], q);
  }
}

// ---------------- policy head (one edge per 16 lanes, grid-stride) ----------------
__global__ __launch_bounds__(256) void policy_kernel(
    const ushort* __restrict__ Ps, const ushort* __restrict__ Pd,
    const int* __restrict__ src, const int* __restrict__ dst,
    const float* __restrict__ edge_attr, const float* __restrict__ Wp1e,
    const float* __restrict__ bp1, const float* __restrict__ Wp2,
    const float* __restrict__ bp2, float* __restrict__ outp) {
  int j = threadIdx.x & 15;
  int gid = (blockIdx.x * 256 + threadIdx.x) >> 4;
  int ngroups = (gridDim.x * 256) >> 4;
  float4 we[12];
#pragma unroll
  for (int k = 0; k < 12; k++) we[k] = *(const float4*)&Wp1e[k * 64 + j * 4];
  float4 b4 = *(const float4*)&bp1[j * 4];
  float4 w2 = *(const float4*)&Wp2[j * 4];
  float bp2c = bp2[0];
  for (int e = gid; e < N_EDGES; e += ngroups) {
    int s = src[e], d = dst[e];
    const float* eap = &edge_attr[(size_t)e * EDIM];
    float4 e0 = *(const float4*)eap;
    float4 e1 = *(const float4*)(eap + 4);
    float4 e2 = *(const float4*)(eap + 8);
    uint2 psu = *(const uint2*)&Ps[(size_t)s * 64 + j * 4];
    uint2 pdu = *(const uint2*)&Pd[(size_t)d * 64 + j * 4];
    float eav[12] = {e0.x, e0.y, e0.z, e0.w, e1.x, e1.y, e1.z, e1.w, e2.x, e2.y, e2.z, e2.w};
    float hx = bflo(psu.x) + bflo(pdu.x) + b4.x;
    float hy = bfhi(psu.x) + bfhi(pdu.x) + b4.y;
    float hz = bflo(psu.y) + bflo(pdu.y) + b4.z;
    float hw = bfhi(psu.y) + bfhi(pdu.y) + b4.w;
#pragma unroll
    for (int k = 0; k < 12; k++) {
      hx = fmaf(eav[k], we[k].x, hx);
      hy = fmaf(eav[k], we[k].y, hy);
      hz = fmaf(eav[k], we[k].z, hz);
      hw = fmaf(eav[k], we[k].w, hw);
    }
    hx = fmaxf(hx, 0.f); hy = fmaxf(hy, 0.f); hz = fmaxf(hz, 0.f); hw = fmaxf(hw, 0.f);
    float v = fmaf(hx, w2.x, fmaf(hy, w2.y, fmaf(hz, w2.z, hw * w2.w)));
    v += __shfl_xor(v, 1);
    v += __shfl_xor(v, 2);
    v += __shfl_xor(v, 4);
    v += __shfl_xor(v, 8);
    if (j == 0) outp[e] = v + bp2c;
  }
}

// ---------------- pooled mean + value head ----------------
__device__ int lower_bound_dev(const int* a, int n, int key) {
  int lo = 0, hi = n;
  while (lo < hi) {
    int mid = (lo + hi) >> 1;
    if (a[mid] < key) lo = mid + 1; else hi = mid;
  }
  return lo;
}

__global__ void poolvalue_kernel(const float* __restrict__ h, const int* __restrict__ batch,
                                 const float* __restrict__ Wv1, const float* __restrict__ bv1,
                                 const float* __restrict__ Wv2, const float* __restrict__ bv2,
                                 float* __restrict__ outv) {
  __shared__ float pl[128];
  __shared__ float hd[64];
  __shared__ int range[2];
  int g = blockIdx.x, t = threadIdx.x;
  if (t == 0) {
    range[0] = lower_bound_dev(batch, N_NODES, g);
    range[1] = lower_bound_dev(batch, N_NODES, g + 1);
  }
  __syncthreads();
  int lo = range[0], hi = range[1];
  float s = 0.f;
  for (int n = lo; n < hi; n++) s += h[(size_t)n * HID + t];
  float cnt = (float)(hi - lo);
  pl[t] = s / fmaxf(cnt, 1.f);
  __syncthreads();
  if (t < 64) {
    float a = bv1[t];
    for (int c = 0; c < 128; c++) a = fmaf(pl[c], Wv1[c * 64 + t], a);
    hd[t] = fmaxf(a, 0.f);
  }
  __syncthreads();
  if (t < 3) {
    float a = bv2[t];
    for (int j = 0; j < 64; j++) a = fmaf(hd[j], Wv2[j * 3 + t], a);
    outv[g * 3 + t] = a;
  }
}

// ---------------- host ----------------
extern "C" void kernel_launch(void* const* d_in, const int* in_sizes, int n_in,
                              void* d_out, int out_size, void* d_ws, size_t ws_size,
                              hipStream_t stream) {
  (void)in_sizes; (void)n_in; (void)out_size; (void)ws_size;
  const float* x    = (const float*)d_in[0];
  const int*   src  = (const int*)d_in[1];
  const int*   dst  = (const int*)d_in[2];
  const int*   batch= (const int*)d_in[3];
  const float* ea   = (const float*)d_in[4];
  const float* Win  = (const float*)d_in[5];
  const float* b_in = (const float*)d_in[6];
  const float* Wl   = (const float*)d_in[7];
  const float* bl   = (const float*)d_in[8];
  const float* Wr   = (const float*)d_in[9];
  const float* br   = (const float*)d_in[10];
  const float* We   = (const float*)d_in[11];
  const float* att  = (const float*)d_in[12];
  const float* bo   = (const float*)d_in[13];
  const float* gamma= (const float*)d_in[14];
  const float* beta = (const float*)d_in[15];
  const float* Wv1  = (const float*)d_in[16];
  const float* bv1  = (const float*)d_in[17];
  const float* Wv2  = (const float*)d_in[18];
  const float* bv2  = (const float*)d_in[19];
  const float* Wp1  = (const float*)d_in[20];
  const float* bp1  = (const float*)d_in[21];
  const float* Wp2  = (const float*)d_in[22];
  const float* bp2  = (const float*)d_in[23];

  float* outv = (float*)d_out;                      // [G,3]
  float* outp = outv + (size_t)N_GRAPHS * 3;        // [E]

  float* hres   = (float*)d_ws;                           // residual / final h (f32)
  ushort* tmp16 = (ushort*)(hres + (size_t)N_NODES * HID); // gat output (bf16)
  ushort* h16   = tmp16 + (size_t)N_NODES * HID;           // inproj bf16
  ushort* xl16  = h16 + (size_t)N_NODES * HID;
  ushort* xr16  = xl16 + (size_t)N_NODES * HID;
  float* stats  = (float*)(xr16 + (size_t)N_NODES * HID);
  ushort* wpk   = (ushort*)(stats + NLAYERS * 256);
  ushort* wppk  = wpk + (size_t)NLAYERS * 4 * 256 * 32;
  int* off    = (int*)(wppk + 4 * 128 * 32);
  int* cursor = off + (N_NODES + 1);
  int* bsum   = cursor + N_NODES;
  uint* erec  = (uint*)(((uintptr_t)(bsum + 256) + 15) & ~(uintptr_t)15);

  const int NB = (N_NODES + 255) / 256;
  const int EB = (N_EDGES + 255) / 256;

  zero_kernel<<<NB, 256, 0, stream>>>(off, cursor, stats, erec);
  count_kernel<<<EB, 256, 0, stream>>>(dst, off);
  scan1_kernel<<<NB, 256, 0, stream>>>(off, bsum);
  scan2_kernel<<<1, 256, 0, stream>>>(bsum, NB);
  scan3_kernel<<<NB, 256, 0, stream>>>(off, bsum);
  scatter_kernel<<<EB, 256, 0, stream>>>(src, dst, ea, off, cursor, erec);
  wprep_kernel<<<(NLAYERS * 4 * 256 * 32 + 255) / 256, 256, 0, stream>>>(Wl, Wr, wpk);
  wprep_pol_kernel<<<(4 * 128 * 32 + 255) / 256, 256, 0, stream>>>(Wp1, wppk);
  inproj_kernel<<<N_NODES / 2, 256, 0, stream>>>(x, Win, b_in, hres, h16);

  const int MB = (N_NODES + 63) / 64;

  for (int l = 0; l < NLAYERS; l++) {
    if (l == 0) {
      gemm_mfma_kernel<256, 128, true, true, false, false, false><<<MB, 256, 0, stream>>>(
          h16, nullptr, nullptr, nullptr, nullptr, nullptr, nullptr,
          wpk, bl, br, xl16, xr16, N_NODES);
    } else if (l & 1) {
      int p = l - 1;
      gemm_mfma_kernel<256, 128, true, true, true, false, false><<<MB, 256, 0, stream>>>(
          nullptr, tmp16, stats + p * 256, gamma + p * HID, beta + p * HID, nullptr, nullptr,
          wpk + (size_t)l * 32768, bl + l * HID, br + l * HID, xl16, xr16, N_NODES);
    } else {
      int p = l - 1;
      gemm_mfma_kernel<256, 128, true, true, true, true, true><<<MB, 256, 0, stream>>>(
          nullptr, tmp16, stats + p * 256, gamma + p * HID, beta + p * HID, hres, hres,
          wpk + (size_t)l * 32768, bl + l * HID, br + l * HID, xl16, xr16, N_NODES);
    }
    gat_kernel<<<GAT_BLOCKS, 256, 0, stream>>>(xl16, xr16, erec, off,
                                               We + (size_t)l * EDIM * HID, att + (size_t)l * HID,
                                               bo + (size_t)l * HID, tmp16);
    bnstats_kernel<<<256, 256, 0, stream>>>(tmp16, stats + l * 256);
  }

  // policy projections: BN of layer 7 fused (+residual, final h -> hres), bf16 out
  ushort* Ps = xl16;
  ushort* Pd = xr16;
  gemm_mfma_kernel<128, 64, false, true, true, true, true><<<MB, 256, 0, stream>>>(
      nullptr, tmp16, stats + 7 * 256, gamma + 7 * HID, beta + 7 * HID, hres, hres,
      wppk, nullptr, nullptr, Ps, Pd, N_NODES);
  policy_kernel<<<2048, 256, 0, stream>>>(Ps, Pd, src, dst, ea,
                                          Wp1 + 256 * 64, bp1, Wp2, bp2, outp);
  poolvalue_kernel<<<N_GRAPHS, 128, 0, stream>>>(hres, batch, Wv1, bv1, Wv2, bv2, outv);
}

// Round 18
// 1095.032 us; speedup vs baseline: 2.7772x; 1.0532x over previous
//
#include <hip/hip_runtime.h>
#include <math.h>

#define N_NODES 50000
#define N_EDGES 500000
#define N_GRAPHS 2048
#define HID 128
#define EDIM 12
#define NLAYERS 8
#define EPS_BN 1e-5f
#define LOG2E 1.44269504088896340736f
#define GAT_BLOCKS 2048
#define GAT_WAVES (GAT_BLOCKS * 4)

typedef __attribute__((ext_vector_type(8))) short short8;
typedef __attribute__((ext_vector_type(4))) float f32x4;
typedef __attribute__((ext_vector_type(2))) float f32x2;
typedef unsigned int uint;
typedef unsigned short ushort;

__device__ inline ushort f2bf(float x) {
  unsigned u = __float_as_uint(x);
  u = (u + 0x7FFFu + ((u >> 16) & 1u)) >> 16;  // RNE
  return (ushort)u;
}
__device__ inline unsigned pk_bf16(float a, float b) {
  return (unsigned)f2bf(a) | ((unsigned)f2bf(b) << 16);
}
__device__ inline float bflo(uint q) { return __uint_as_float(q << 16); }
__device__ inline float bfhi(uint q) { return __uint_as_float(q & 0xFFFF0000u); }
__device__ inline f32x2 pfma(f32x2 a, f32x2 b, f32x2 c) {
  return __builtin_elementwise_fma(a, b, c);
}
// butterfly add, pure-VALU DPP (ctrl must be a literal)
template <int CTRL>
__device__ inline float dpp_add(float v) {
  int s = __builtin_amdgcn_update_dpp(0, __float_as_int(v), CTRL, 0xF, 0xF, true);
  return v + __int_as_float(s);
}
// 8-lane butterfly (head = 8 lanes x 4ch): xor1, xor2, mirror-within-8
#define RED8(v)               \
  v = dpp_add<0xB1>(v);       \
  v = dpp_add<0x4E>(v);       \
  v = dpp_add<0x141>(v);

// ---------------- CSR build ----------------
__global__ void count_kernel(const int* __restrict__ dst, int* __restrict__ deg) {
  int e = blockIdx.x * 256 + threadIdx.x;
  if (e < N_EDGES) atomicAdd(&deg[dst[e]], 1);
}

__global__ void scan1_kernel(int* __restrict__ off, int* __restrict__ bsum) {
  __shared__ int s[256];
  int t = threadIdx.x; int n = blockIdx.x * 256 + t;
  int x = (n < N_NODES) ? off[n] : 0;
  s[t] = x; __syncthreads();
  for (int o = 1; o < 256; o <<= 1) {
    int v = (t >= o) ? s[t - o] : 0;
    __syncthreads(); s[t] += v; __syncthreads();
  }
  if (n < N_NODES) off[n] = s[t] - x;
  if (t == 255) bsum[blockIdx.x] = s[255];
}

__global__ void scan2_kernel(int* __restrict__ bsum, int nb) {
  __shared__ int s[256];
  int t = threadIdx.x;
  int x = (t < nb) ? bsum[t] : 0;
  s[t] = x; __syncthreads();
  for (int o = 1; o < 256; o <<= 1) {
    int v = (t >= o) ? s[t - o] : 0;
    __syncthreads(); s[t] += v; __syncthreads();
  }
  if (t < nb) bsum[t] = s[t] - x;
}

__global__ void scan3_kernel(int* __restrict__ off, const int* __restrict__ bsum) {
  int t = threadIdx.x; int n = blockIdx.x * 256 + t;
  if (n < N_NODES) off[n] += bsum[blockIdx.x];
  if (n == 0 && blockIdx.x == 0) off[N_NODES] = N_EDGES;
}

// erec[pos] = {src, pad, ea_bf16 x6} (8 dwords, 32B)
__global__ void scatter_kernel(const int* __restrict__ src, const int* __restrict__ dst,
                               const float* __restrict__ ea,
                               const int* __restrict__ off, int* __restrict__ cursor,
                               uint* __restrict__ erec) {
  int e = blockIdx.x * 256 + threadIdx.x;
  if (e < N_EDGES) {
    int d = dst[e];
    int p = atomicAdd(&cursor[d], 1);
    int pos = off[d] + p;
    const float* eap = &ea[(size_t)e * EDIM];
    float4 e0 = *(const float4*)eap;
    float4 e1 = *(const float4*)(eap + 4);
    float4 e2 = *(const float4*)(eap + 8);
    uint4 q0, q1;
    q0.x = (uint)src[e]; q0.y = 0u;
    q0.z = pk_bf16(e0.x, e0.y); q0.w = pk_bf16(e0.z, e0.w);
    q1.x = pk_bf16(e1.x, e1.y); q1.y = pk_bf16(e1.z, e1.w);
    q1.z = pk_bf16(e2.x, e2.y); q1.w = pk_bf16(e2.z, e2.w);
    uint* o = &erec[(size_t)pos * 8];
    *(uint4*)o = q0;
    *(uint4*)(o + 4) = q1;
  }
}

// ---------------- fused prep: zero CSR/stats/pad + pack all weights ----------------
__global__ void prep_kernel(int* __restrict__ off, int* __restrict__ cursor,
                            float* __restrict__ stats, uint* __restrict__ erec,
                            const float* __restrict__ Wl, const float* __restrict__ Wr,
                            ushort* __restrict__ wpk,
                            const float* __restrict__ Wp1, ushort* __restrict__ wppk) {
  int i = blockIdx.x * 256 + threadIdx.x;
  if (i < N_NODES) { off[i] = 0; cursor[i] = 0; }
  if (i < NLAYERS * 8 * 256) stats[i] = 0.f;
  if (i < 32) erec[(size_t)N_EDGES * 8 + i] = 0u;  // 4 pad records (src=0)
  if (i < NLAYERS * 4 * 256 * 32) {
    int kk = i & 31;
    int cc = (i >> 5) & 255;
    int kb = (i >> 13) & 3;
    int layer = i >> 15;
    int k = kb * 32 + kk;
    float v = (cc < 128) ? Wl[((size_t)layer * 128 + k) * 128 + cc]
                         : Wr[((size_t)layer * 128 + k) * 128 + (cc - 128)];
    wpk[i] = f2bf(v);
  }
  if (i < 4 * 128 * 32) {
    int kk = i & 31;
    int cc = (i >> 5) & 127;
    int kb = i >> 12;
    int k = kb * 32 + kk;
    float v = (cc < 64) ? Wp1[(size_t)k * 64 + cc] : Wp1[(size_t)(128 + k) * 64 + (cc - 64)];
    wppk[i] = f2bf(v);
  }
}

// ---------------- input projection (writes f32 hres + bf16 h16) ----------------
__global__ void inproj_kernel(const float* __restrict__ x, const float* __restrict__ Win,
                              const float* __restrict__ b_in, float* __restrict__ h,
                              ushort* __restrict__ h16) {
  __shared__ float xs[44];
  int t = threadIdx.x;
  int n0 = blockIdx.x * 2;
  if (t < 44) xs[t] = x[n0 * 22 + t];
  __syncthreads();
  int c = t & 127, half = t >> 7;
  int n = n0 + half;
  if (n < N_NODES) {
    float acc = b_in[c];
#pragma unroll
    for (int k = 0; k < 22; k++) acc = fmaf(xs[half * 22 + k], Win[k * HID + c], acc);
    float v = fmaxf(acc, 0.f);
    h[(size_t)n * HID + c] = v;
    h16[(size_t)n * HID + c] = f2bf(v);
  }
}

// ---------------- MFMA GEMM (optionally BN+residual+relu fused on input) --------
// BNFUSE: stats8 = 8 partial slices [8][256]; sum slices, then normalize f32 T.
template <int NOUT, int SPLIT, bool BIAS, bool OUTBF16, bool BNFUSE, bool RESID, bool WRITEH>
__global__ __launch_bounds__(256) void gemm_mfma_kernel(
    const ushort* __restrict__ A16, const float* __restrict__ T,
    const float* __restrict__ stats8, const float* __restrict__ gamma,
    const float* __restrict__ beta, const float* __restrict__ res,
    float* __restrict__ hout,
    const ushort* __restrict__ Wpk, const float* __restrict__ b1,
    const float* __restrict__ b2, void* __restrict__ C1v, void* __restrict__ C2v,
    int nrows) {
  __shared__ ushort As[64][136];  // +8 pad
  int t = threadIdx.x;
  int brow = blockIdx.x * 64;
  if constexpr (!BNFUSE) {
#pragma unroll
    for (int i = 0; i < 4; i++) {
      int f = t + i * 256;
      int r = f >> 4, cg = (f & 15) * 8;
      int g = brow + r;
      uint4 v = make_uint4(0, 0, 0, 0);
      if (g < nrows) v = *(const uint4*)&A16[(size_t)g * HID + cg];
      *(uint4*)&As[r][cg] = v;
    }
  } else {
    int cg = (t & 31) * 4;
    int r0 = t >> 5;
    const float invN = 1.f / (float)N_NODES;
    float s4[4] = {0.f, 0.f, 0.f, 0.f};
    float q4[4] = {0.f, 0.f, 0.f, 0.f};
#pragma unroll
    for (int sl = 0; sl < 8; sl++) {
      float4 a = *(const float4*)&stats8[sl * 256 + cg];
      float4 b = *(const float4*)&stats8[sl * 256 + 128 + cg];
      s4[0] += a.x; s4[1] += a.y; s4[2] += a.z; s4[3] += a.w;
      q4[0] += b.x; q4[1] += b.y; q4[2] += b.z; q4[3] += b.w;
    }
    float4 gm = *(const float4*)&gamma[cg];
    float4 bt = *(const float4*)&beta[cg];
    float g4[4] = {gm.x, gm.y, gm.z, gm.w};
    float bb4[4] = {bt.x, bt.y, bt.z, bt.w};
    float scl[4], shf[4];
#pragma unroll
    for (int k = 0; k < 4; k++) {
      float mu = s4[k] * invN;
      float var = q4[k] * invN - mu * mu;
      float rs = rsqrtf(var + EPS_BN);
      scl[k] = g4[k] * rs;
      shf[k] = bb4[k] - mu * scl[k];
    }
#pragma unroll
    for (int rr = 0; rr < 8; rr++) {
      int r = r0 + rr * 8;
      int g = brow + r;
      float4 tv = make_float4(0.f, 0.f, 0.f, 0.f);
      if (g < nrows) tv = *(const float4*)&T[(size_t)g * HID + cg];
      float o0 = fmaf(tv.x, scl[0], shf[0]);
      float o1 = fmaf(tv.y, scl[1], shf[1]);
      float o2 = fmaf(tv.z, scl[2], shf[2]);
      float o3 = fmaf(tv.w, scl[3], shf[3]);
      if constexpr (RESID) {
        if (g < nrows) {
          float4 rv = *(const float4*)&res[(size_t)g * HID + cg];
          o0 += rv.x; o1 += rv.y; o2 += rv.z; o3 += rv.w;
        }
      }
      o0 = fmaxf(o0, 0.f); o1 = fmaxf(o1, 0.f);
      o2 = fmaxf(o2, 0.f); o3 = fmaxf(o3, 0.f);
      if constexpr (WRITEH) {
        if (g < nrows) {
          float4 ov = make_float4(o0, o1, o2, o3);
          *(float4*)&hout[(size_t)g * HID + cg] = ov;
        }
      }
      *(uint2*)&As[r][cg] = make_uint2(pk_bf16(o0, o1), pk_bf16(o2, o3));
    }
  }
  __syncthreads();
  int lane = t & 63, wave = t >> 6;
  int arow = wave * 16 + (lane & 15);
  int k8 = (lane >> 4) * 8;
  constexpr int NT = NOUT / 16;
  f32x4 acc[NT];
#pragma unroll
  for (int n = 0; n < NT; n++) acc[n] = (f32x4){0.f, 0.f, 0.f, 0.f};
#pragma unroll
  for (int kb = 0; kb < 4; kb++) {
    short8 a = *(const short8*)&As[arow][kb * 32 + k8];
#pragma unroll
    for (int n = 0; n < NT; n++) {
      int col = n * 16 + (lane & 15);
      short8 b = *(const short8*)&Wpk[((size_t)(kb * NOUT + col)) * 32 + k8];
      acc[n] = __builtin_amdgcn_mfma_f32_16x16x32_bf16(a, b, acc[n], 0, 0, 0);
    }
  }
  // C/D: col = lane&15, row = (lane>>4)*4 + j
  int rbase = brow + wave * 16 + (lane >> 4) * 4;
  int ccol = lane & 15;
#pragma unroll
  for (int n = 0; n < NT; n++) {
    int col = n * 16 + ccol;
    float bias = 0.f;
    if (BIAS) bias = (col < SPLIT) ? b1[col] : b2[col - SPLIT];
    int colw = (col < SPLIT) ? col : col - SPLIT;
#pragma unroll
    for (int j = 0; j < 4; j++) {
      int row = rbase + j;
      if (row < nrows) {
        float v = acc[n][j] + bias;
        if (OUTBF16) {
          ushort* dstp = (ushort*)((col < SPLIT) ? C1v : C2v);
          dstp[(size_t)row * SPLIT + colw] = f2bf(v);
        } else {
          float* dstp = (float*)((col < SPLIT) ? C1v : C2v);
          dstp[(size_t)row * SPLIT + colw] = v;
        }
      }
    }
  }
}

// ---------------- GATv2 aggregation + fused BN partial stats (f32 out) ----------
// PERSISTENT waves: 2048 blocks x 4 waves; per node: 2 EDGES/wave (lanes 0-31
// even, 32-63 odd; 4 ch/lane), online-softmax per half merged via shfl_xor(32).
// f32 output (precision margin); register BN partials -> LDS reduce -> atomicAdd
// into stats slice (blockIdx&7); consuming GEMM sums 8 slices.
#define GAT_EDGE4(ra, rb, xw, OKEXPR)                                        \
  {                                                                          \
    f32x2 xa01 = (f32x2){bflo(xw.x), bfhi(xw.x)};                            \
    f32x2 xa23 = (f32x2){bflo(xw.y), bfhi(xw.y)};                            \
    f32x2 ep01 = xa01 + xr01;                                                \
    f32x2 ep23 = xa23 + xr23;                                                \
    uint q; float lo, hi;                                                    \
    q = ra.z; lo = bflo(q); hi = bfhi(q);                                    \
    ep01 = pfma((f32x2){lo, lo}, wk01[0], ep01);                             \
    ep23 = pfma((f32x2){lo, lo}, wk23[0], ep23);                             \
    ep01 = pfma((f32x2){hi, hi}, wk01[1], ep01);                             \
    ep23 = pfma((f32x2){hi, hi}, wk23[1], ep23);                             \
    q = ra.w; lo = bflo(q); hi = bfhi(q);                                    \
    ep01 = pfma((f32x2){lo, lo}, wk01[2], ep01);                             \
    ep23 = pfma((f32x2){lo, lo}, wk23[2], ep23);                             \
    ep01 = pfma((f32x2){hi, hi}, wk01[3], ep01);                             \
    ep23 = pfma((f32x2){hi, hi}, wk23[3], ep23);                             \
    q = rb.x; lo = bflo(q); hi = bfhi(q);                                    \
    ep01 = pfma((f32x2){lo, lo}, wk01[4], ep01);                             \
    ep23 = pfma((f32x2){lo, lo}, wk23[4], ep23);                             \
    ep01 = pfma((f32x2){hi, hi}, wk01[5], ep01);                             \
    ep23 = pfma((f32x2){hi, hi}, wk23[5], ep23);                             \
    q = rb.y; lo = bflo(q); hi = bfhi(q);                                    \
    ep01 = pfma((f32x2){lo, lo}, wk01[6], ep01);                             \
    ep23 = pfma((f32x2){lo, lo}, wk23[6], ep23);                             \
    ep01 = pfma((f32x2){hi, hi}, wk01[7], ep01);                             \
    ep23 = pfma((f32x2){hi, hi}, wk23[7], ep23);                             \
    q = rb.z; lo = bflo(q); hi = bfhi(q);                                    \
    ep01 = pfma((f32x2){lo, lo}, wk01[8], ep01);                             \
    ep23 = pfma((f32x2){lo, lo}, wk23[8], ep23);                             \
    ep01 = pfma((f32x2){hi, hi}, wk01[9], ep01);                             \
    ep23 = pfma((f32x2){hi, hi}, wk23[9], ep23);                             \
    q = rb.w; lo = bflo(q); hi = bfhi(q);                                    \
    ep01 = pfma((f32x2){lo, lo}, wk01[10], ep01);                            \
    ep23 = pfma((f32x2){lo, lo}, wk23[10], ep23);                            \
    ep01 = pfma((f32x2){hi, hi}, wk01[11], ep01);                            \
    ep23 = pfma((f32x2){hi, hi}, wk23[11], ep23);                            \
    f32x2 s01 = __builtin_elementwise_max(ep01, ep01 * (f32x2){0.2f, 0.2f}); \
    f32x2 s23 = __builtin_elementwise_max(ep23, ep23 * (f32x2){0.2f, 0.2f}); \
    float v = fmaf(s01.x, at4.x,                                             \
              fmaf(s01.y, at4.y, fmaf(s23.x, at4.z, s23.y * at4.w)));        \
    RED8(v)                                                                  \
    bool ok = (OKEXPR);                                                      \
    float dm = v - m;                                                        \
    float e = __builtin_amdgcn_exp2f(-fabsf(dm));                            \
    bool big = dm > 0.f;                                                     \
    float sc = (big && ok) ? e : 1.f;                                        \
    float p = ok ? (big ? 1.f : e) : 0.f;                                    \
    m = (ok && big) ? v : m;                                                 \
    d = fmaf(d, sc, p);                                                      \
    acc01 = pfma(acc01, (f32x2){sc, sc}, (f32x2){p, p} * xa01);              \
    acc23 = pfma(acc23, (f32x2){sc, sc}, (f32x2){p, p} * xa23);              \
  }

__global__ __launch_bounds__(256) void gat_kernel(
    const ushort* __restrict__ xl16, const ushort* __restrict__ xr16,
    const uint* __restrict__ erec, const int* __restrict__ off,
    const float* __restrict__ Wel, const float* __restrict__ attl,
    const float* __restrict__ bol, float* __restrict__ out,
    float* __restrict__ stats) {
  int lane = threadIdx.x & 63;
  int gwave = blockIdx.x * 4 + (threadIdx.x >> 6);
  int half = lane >> 5;          // 0: even edges, 1: odd edges
  int c0 = (lane & 31) * 4;      // 4 channels per lane

  // layer constants: loaded ONCE per wave
  f32x2 wk01[12], wk23[12];
#pragma unroll
  for (int k = 0; k < 12; k++) {
    float4 w = *(const float4*)&Wel[k * HID + c0];
    wk01[k] = (f32x2){w.x, w.y};
    wk23[k] = (f32x2){w.z, w.w};
  }
  float4 at4 = *(const float4*)&attl[c0];
  at4.x *= LOG2E; at4.y *= LOG2E; at4.z *= LOG2E; at4.w *= LOG2E;
  float4 bo = *(const float4*)&bol[c0];

  float ps0 = 0.f, ps1 = 0.f, ps2 = 0.f, ps3 = 0.f;
  float pq0 = 0.f, pq1 = 0.f, pq2 = 0.f, pq3 = 0.f;

  for (int node = gwave; node < N_NODES; node += GAT_WAVES) {
    uint2 xru = *(const uint2*)&xr16[((uint)node << 7) + c0];
    f32x2 xr01 = (f32x2){bflo(xru.x), bfhi(xru.x)};
    f32x2 xr23 = (f32x2){bflo(xru.y), bfhi(xru.y)};

    int is = off[node], deg = off[node + 1] - is;

    float m = -INFINITY, d = 0.f;
    f32x2 acc01 = (f32x2){0.f, 0.f};
    f32x2 acc23 = (f32x2){0.f, 0.f};

    if (deg > 0) {
      const uint* pe = erec + ((size_t)is + half) * 8;
      uint4 Ra = *(const uint4*)pe, Rb = *(const uint4*)(pe + 4);
      uint2 xw = *(const uint2*)&xl16[(Ra.x << 7) + c0];
      int full = deg >> 1;
      for (int i = 0; i < full; i++) {
        const uint* pn = pe + 16;
        uint4 Na = *(const uint4*)pn, Nb = *(const uint4*)(pn + 4);
        uint2 xn = *(const uint2*)&xl16[(Na.x << 7) + c0];
        GAT_EDGE4(Ra, Rb, xw, true)
        Ra = Na; Rb = Nb; xw = xn; pe = pn;
      }
      if (deg & 1) GAT_EDGE4(Ra, Rb, xw, half == 0)
    }

    // merge half-wave chains
    float mo = __shfl_xor(m, 32);
    float dd = __shfl_xor(d, 32);
    f32x2 o01, o23;
    o01.x = __shfl_xor(acc01.x, 32); o01.y = __shfl_xor(acc01.y, 32);
    o23.x = __shfl_xor(acc23.x, 32); o23.y = __shfl_xor(acc23.y, 32);
    float mn = fmaxf(m, mo);
    float wS = (m > -INFINITY) ? __builtin_amdgcn_exp2f(m - mn) : 0.f;
    float wO = (mo > -INFINITY) ? __builtin_amdgcn_exp2f(mo - mn) : 0.f;
    float den = d * wS + dd * wO;
    f32x2 a01 = acc01 * (f32x2){wS, wS} + o01 * (f32x2){wO, wO};
    f32x2 a23 = acc23 * (f32x2){wS, wS} + o23 * (f32x2){wO, wO};
    float inv = 1.f / (den + 1e-16f);
    if (half == 0) {
      float r0 = fmaf(a01.x, inv, bo.x);
      float r1 = fmaf(a01.y, inv, bo.y);
      float r2 = fmaf(a23.x, inv, bo.z);
      float r3 = fmaf(a23.y, inv, bo.w);
      *(float4*)&out[((uint)node << 7) + c0] = make_float4(r0, r1, r2, r3);
      ps0 += r0; pq0 = fmaf(r0, r0, pq0);
      ps1 += r1; pq1 = fmaf(r1, r1, pq1);
      ps2 += r2; pq2 = fmaf(r2, r2, pq2);
      ps3 += r3; pq3 = fmaf(r3, r3, pq3);
    }
  }

  // block-level stat reduce -> one atomicAdd per channel into slice blockIdx&7
  __shared__ float ls[4][128], lq[4][128];
  int wv = threadIdx.x >> 6;
  if (half == 0) {
    ls[wv][c0 + 0] = ps0; ls[wv][c0 + 1] = ps1;
    ls[wv][c0 + 2] = ps2; ls[wv][c0 + 3] = ps3;
    lq[wv][c0 + 0] = pq0; lq[wv][c0 + 1] = pq1;
    lq[wv][c0 + 2] = pq2; lq[wv][c0 + 3] = pq3;
  }
  __syncthreads();
  int t = threadIdx.x;
  float* slice = stats + (blockIdx.x & 7) * 256;
  if (t < 128) {
    atomicAdd(&slice[t], ls[0][t] + ls[1][t] + ls[2][t] + ls[3][t]);
  } else if (t < 256) {
    int c = t - 128;
    atomicAdd(&slice[128 + c], lq[0][c] + lq[1][c] + lq[2][c] + lq[3][c]);
  }
}

// ---------------- fused heads: policy (blocks 0..2047) + pool/value (2048..4095) ----
__device__ int lower_bound_dev(const int* a, int n, int key) {
  int lo = 0, hi = n;
  while (lo < hi) {
    int mid = (lo + hi) >> 1;
    if (a[mid] < key) lo = mid + 1; else hi = mid;
  }
  return lo;
}

__global__ __launch_bounds__(256) void heads_kernel(
    const float* __restrict__ Ps, const float* __restrict__ Pd,
    const int* __restrict__ src, const int* __restrict__ dst,
    const float* __restrict__ edge_attr, const float* __restrict__ Wp1e,
    const float* __restrict__ bp1, const float* __restrict__ Wp2,
    const float* __restrict__ bp2, float* __restrict__ outp,
    const float* __restrict__ h, const int* __restrict__ batch,
    const float* __restrict__ Wv1, const float* __restrict__ bv1,
    const float* __restrict__ Wv2, const float* __restrict__ bv2,
    float* __restrict__ outv) {
  if (blockIdx.x < 2048) {
    // ---- policy: one edge per 16 lanes, grid-stride over 2048 blocks ----
    int j = threadIdx.x & 15;
    int gid = (blockIdx.x * 256 + threadIdx.x) >> 4;
    const int ngroups = (2048 * 256) >> 4;
    float4 we[12];
#pragma unroll
    for (int k = 0; k < 12; k++) we[k] = *(const float4*)&Wp1e[k * 64 + j * 4];
    float4 b4 = *(const float4*)&bp1[j * 4];
    float4 w2 = *(const float4*)&Wp2[j * 4];
    float bp2c = bp2[0];
    for (int e = gid; e < N_EDGES; e += ngroups) {
      int s = src[e], d = dst[e];
      const float* eap = &edge_attr[(size_t)e * EDIM];
      float4 e0 = *(const float4*)eap;
      float4 e1 = *(const float4*)(eap + 4);
      float4 e2 = *(const float4*)(eap + 8);
      float4 psv = *(const float4*)&Ps[(size_t)s * 64 + j * 4];
      float4 pdv = *(const float4*)&Pd[(size_t)d * 64 + j * 4];
      float eav[12] = {e0.x, e0.y, e0.z, e0.w, e1.x, e1.y, e1.z, e1.w, e2.x, e2.y, e2.z, e2.w};
      float hx = psv.x + pdv.x + b4.x;
      float hy = psv.y + pdv.y + b4.y;
      float hz = psv.z + pdv.z + b4.z;
      float hw = psv.w + pdv.w + b4.w;
#pragma unroll
      for (int k = 0; k < 12; k++) {
        hx = fmaf(eav[k], we[k].x, hx);
        hy = fmaf(eav[k], we[k].y, hy);
        hz = fmaf(eav[k], we[k].z, hz);
        hw = fmaf(eav[k], we[k].w, hw);
      }
      hx = fmaxf(hx, 0.f); hy = fmaxf(hy, 0.f); hz = fmaxf(hz, 0.f); hw = fmaxf(hw, 0.f);
      float v = fmaf(hx, w2.x, fmaf(hy, w2.y, fmaf(hz, w2.z, hw * w2.w)));
      v += __shfl_xor(v, 1);
      v += __shfl_xor(v, 2);
      v += __shfl_xor(v, 4);
      v += __shfl_xor(v, 8);
      if (j == 0) outp[e] = v + bp2c;
    }
  } else {
    // ---- pooled mean + value head: one graph per block ----
    __shared__ float pl[128];
    __shared__ float hd[64];
    __shared__ int range[2];
    int g = blockIdx.x - 2048, t = threadIdx.x;
    if (t == 0) {
      range[0] = lower_bound_dev(batch, N_NODES, g);
      range[1] = lower_bound_dev(batch, N_NODES, g + 1);
    }
    __syncthreads();
    int lo = range[0], hi = range[1];
    if (t < 128) {
      float s = 0.f;
      for (int n = lo; n < hi; n++) s += h[(size_t)n * HID + t];
      float cnt = (float)(hi - lo);
      pl[t] = s / fmaxf(cnt, 1.f);
    }
    __syncthreads();
    if (t < 64) {
      float a = bv1[t];
      for (int c = 0; c < 128; c++) a = fmaf(pl[c], Wv1[c * 64 + t], a);
      hd[t] = fmaxf(a, 0.f);
    }
    __syncthreads();
    if (t < 3) {
      float a = bv2[t];
      for (int j = 0; j < 64; j++) a = fmaf(hd[j], Wv2[j * 3 + t], a);
      outv[g * 3 + t] = a;
    }
  }
}

// ---------------- host ----------------
extern "C" void kernel_launch(void* const* d_in, const int* in_sizes, int n_in,
                              void* d_out, int out_size, void* d_ws, size_t ws_size,
                              hipStream_t stream) {
  (void)in_sizes; (void)n_in; (void)out_size; (void)ws_size;
  const float* x    = (const float*)d_in[0];
  const int*   src  = (const int*)d_in[1];
  const int*   dst  = (const int*)d_in[2];
  const int*   batch= (const int*)d_in[3];
  const float* ea   = (const float*)d_in[4];
  const float* Win  = (const float*)d_in[5];
  const float* b_in = (const float*)d_in[6];
  const float* Wl   = (const float*)d_in[7];
  const float* bl   = (const float*)d_in[8];
  const float* Wr   = (const float*)d_in[9];
  const float* br   = (const float*)d_in[10];
  const float* We   = (const float*)d_in[11];
  const float* att  = (const float*)d_in[12];
  const float* bo   = (const float*)d_in[13];
  const float* gamma= (const float*)d_in[14];
  const float* beta = (const float*)d_in[15];
  const float* Wv1  = (const float*)d_in[16];
  const float* bv1  = (const float*)d_in[17];
  const float* Wv2  = (const float*)d_in[18];
  const float* bv2  = (const float*)d_in[19];
  const float* Wp1  = (const float*)d_in[20];
  const float* bp1  = (const float*)d_in[21];
  const float* Wp2  = (const float*)d_in[22];
  const float* bp2  = (const float*)d_in[23];

  float* outv = (float*)d_out;                      // [G,3]
  float* outp = outv + (size_t)N_GRAPHS * 3;        // [E]

  float* hres   = (float*)d_ws;                            // residual / final h (f32)
  float* tmp    = hres + (size_t)N_NODES * HID;            // gat output (f32)
  ushort* h16   = (ushort*)(tmp + (size_t)N_NODES * HID);  // inproj bf16
  ushort* xl16  = h16 + (size_t)N_NODES * HID;
  ushort* xr16  = xl16 + (size_t)N_NODES * HID;
  float* stats  = (float*)(xr16 + (size_t)N_NODES * HID);  // [NLAYERS][8][256]
  ushort* wpk   = (ushort*)(stats + NLAYERS * 8 * 256);
  ushort* wppk  = wpk + (size_t)NLAYERS * 4 * 256 * 32;
  int* off    = (int*)(wppk + 4 * 128 * 32);
  int* cursor = off + (N_NODES + 1);
  int* bsum   = cursor + N_NODES;
  uint* erec  = (uint*)(((uintptr_t)(bsum + 256) + 15) & ~(uintptr_t)15);

  const int NB = (N_NODES + 255) / 256;
  const int EB = (N_EDGES + 255) / 256;
  const int PB = (NLAYERS * 4 * 256 * 32 + 255) / 256;

  prep_kernel<<<PB, 256, 0, stream>>>(off, cursor, stats, erec, Wl, Wr, wpk, Wp1, wppk);
  count_kernel<<<EB, 256, 0, stream>>>(dst, off);
  scan1_kernel<<<NB, 256, 0, stream>>>(off, bsum);
  scan2_kernel<<<1, 256, 0, stream>>>(bsum, NB);
  scan3_kernel<<<NB, 256, 0, stream>>>(off, bsum);
  scatter_kernel<<<EB, 256, 0, stream>>>(src, dst, ea, off, cursor, erec);
  inproj_kernel<<<N_NODES / 2, 256, 0, stream>>>(x, Win, b_in, hres, h16);

  const int MB = (N_NODES + 63) / 64;

  for (int l = 0; l < NLAYERS; l++) {
    if (l == 0) {
      gemm_mfma_kernel<256, 128, true, true, false, false, false><<<MB, 256, 0, stream>>>(
          h16, nullptr, nullptr, nullptr, nullptr, nullptr, nullptr,
          wpk, bl, br, xl16, xr16, N_NODES);
    } else if (l & 1) {
      int p = l - 1;
      gemm_mfma_kernel<256, 128, true, true, true, false, false><<<MB, 256, 0, stream>>>(
          nullptr, tmp, stats + p * 2048, gamma + p * HID, beta + p * HID, nullptr, nullptr,
          wpk + (size_t)l * 32768, bl + l * HID, br + l * HID, xl16, xr16, N_NODES);
    } else {
      int p = l - 1;
      gemm_mfma_kernel<256, 128, true, true, true, true, true><<<MB, 256, 0, stream>>>(
          nullptr, tmp, stats + p * 2048, gamma + p * HID, beta + p * HID, hres, hres,
          wpk + (size_t)l * 32768, bl + l * HID, br + l * HID, xl16, xr16, N_NODES);
    }
    gat_kernel<<<GAT_BLOCKS, 256, 0, stream>>>(xl16, xr16, erec, off,
                                               We + (size_t)l * EDIM * HID, att + (size_t)l * HID,
                                               bo + (size_t)l * HID, tmp, stats + l * 2048);
  }

  // policy projections: BN of layer 7 fused (+residual, final h -> hres), f32 out
  float* Ps = (float*)xl16;   // N*64 f32 == N*128 bf16 bytes
  float* Pd = (float*)xr16;
  gemm_mfma_kernel<128, 64, false, false, true, true, true><<<MB, 256, 0, stream>>>(
      nullptr, tmp, stats + 7 * 2048, gamma + 7 * HID, beta + 7 * HID, hres, hres,
      wppk, nullptr, nullptr, Ps, Pd, N_NODES);
  heads_kernel<<<4096, 256, 0, stream>>>(Ps, Pd, src, dst, ea,
                                         Wp1 + 256 * 64, bp1, Wp2, bp2, outp,
                                         hres, batch, Wv1, bv1, Wv2, bv2, outv);
}